// Round 7
// baseline (585.309 us; speedup 1.0000x reference)
//
#include <hip/hip_runtime.h>
#include <hip/hip_bf16.h>

// B=2, N=512, FDIM=1024, HEADS=4, DH=256, AH=256, HID=512, OUT=128, NCLS=10
// NN=262144, rank = 52429. Inputs fp32, output fp32[20].

// ================= 64x64 fp32 GEMM (8x8/lane, wave-private k-slices) =================
// ksplit>1: z%ksplit = K-chunk (atomicAdd into zeroed C), z/ksplit = B2/C2 select.
__global__ __launch_bounds__(256) void gemm64_nt(
    const float* __restrict__ A, const float* __restrict__ Bm, float* __restrict__ C,
    int K, int lda, int ldb, int ldc, const float* __restrict__ bias,
    const float* __restrict__ Bm2, float* __restrict__ C2, const float* __restrict__ bias2,
    int ksplit)
{
    if (ksplit > 1){
        int z = blockIdx.z;
        int kz = z % ksplit;
        if (z / ksplit){ Bm = Bm2; C = C2; bias = bias2; }
        A += (size_t)kz * K; Bm += (size_t)kz * K;
        if (kz) bias = nullptr;
    } else if (blockIdx.z){
        Bm = Bm2; C = C2; bias = bias2;
    }
    __shared__ float As[64][64], Bs[64][64];
    int t = threadIdx.x;
    int m0 = blockIdx.y*64, n0 = blockIdx.x*64;
    int w = t>>6, lane = t&63;
    int mi = lane>>3, ni = lane&7;
    int kc = w*16;                            // wave's private k-slice in the tile
    const float* Ar = A + (size_t)(m0+lane)*lda + kc;
    const float* Br = Bm + (size_t)(n0+lane)*ldb + kc;
    float4 pa[4], pb[4];
    #pragma unroll
    for (int j=0;j<4;++j){ pa[j]=*(const float4*)(Ar+j*4); pb[j]=*(const float4*)(Br+j*4); }
    float acc[8][8] = {};
    for (int k0=0; k0<K; k0+=64){
        #pragma unroll
        for (int j=0;j<4;++j){
            As[kc+j*4+0][lane]=pa[j].x; As[kc+j*4+1][lane]=pa[j].y;
            As[kc+j*4+2][lane]=pa[j].z; As[kc+j*4+3][lane]=pa[j].w;
            Bs[kc+j*4+0][lane]=pb[j].x; Bs[kc+j*4+1][lane]=pb[j].y;
            Bs[kc+j*4+2][lane]=pb[j].z; Bs[kc+j*4+3][lane]=pb[j].w;
        }
        if (k0+64 < K){
            #pragma unroll
            for (int j=0;j<4;++j){
                pa[j]=*(const float4*)(Ar+k0+64+j*4);
                pb[j]=*(const float4*)(Br+k0+64+j*4);
            }
        }
        #pragma unroll
        for (int kk=0; kk<16; ++kk){
            float4 a0=*(const float4*)&As[kc+kk][mi*8], a1=*(const float4*)&As[kc+kk][mi*8+4];
            float4 b0=*(const float4*)&Bs[kc+kk][ni*8], b1=*(const float4*)&Bs[kc+kk][ni*8+4];
            float am[8]={a0.x,a0.y,a0.z,a0.w,a1.x,a1.y,a1.z,a1.w};
            float bn[8]={b0.x,b0.y,b0.z,b0.w,b1.x,b1.y,b1.z,b1.w};
            #pragma unroll
            for (int i=0;i<8;++i)
                #pragma unroll
                for (int j2=0;j2<8;++j2) acc[i][j2] += am[i]*bn[j2];
        }
    }
    // ---- reduce 4 wave k-partials through LDS (reuse As/Bs as scratch) ----
    __syncthreads();
    float* s0 = &As[0][0]; float* s1 = &Bs[0][0];
    if (w>=2){
        float* d = (w==2)? s0 : s1;
        #pragma unroll
        for (int i=0;i<8;++i){
            *(float4*)&d[(mi*8+i)*64+ni*8]   = make_float4(acc[i][0],acc[i][1],acc[i][2],acc[i][3]);
            *(float4*)&d[(mi*8+i)*64+ni*8+4] = make_float4(acc[i][4],acc[i][5],acc[i][6],acc[i][7]);
        }
    }
    __syncthreads();
    if (w<2){
        const float* sv = (w==0)? s0 : s1;
        #pragma unroll
        for (int i=0;i<8;++i){
            float4 v0=*(const float4*)&sv[(mi*8+i)*64+ni*8];
            float4 v1=*(const float4*)&sv[(mi*8+i)*64+ni*8+4];
            acc[i][0]+=v0.x; acc[i][1]+=v0.y; acc[i][2]+=v0.z; acc[i][3]+=v0.w;
            acc[i][4]+=v1.x; acc[i][5]+=v1.y; acc[i][6]+=v1.z; acc[i][7]+=v1.w;
        }
    }
    __syncthreads();
    if (w==1){
        #pragma unroll
        for (int i=0;i<8;++i){
            *(float4*)&s0[(mi*8+i)*64+ni*8]   = make_float4(acc[i][0],acc[i][1],acc[i][2],acc[i][3]);
            *(float4*)&s0[(mi*8+i)*64+ni*8+4] = make_float4(acc[i][4],acc[i][5],acc[i][6],acc[i][7]);
        }
    }
    __syncthreads();
    if (w==0){
        #pragma unroll
        for (int i=0;i<8;++i){
            float4 v0=*(const float4*)&s0[(mi*8+i)*64+ni*8];
            float4 v1=*(const float4*)&s0[(mi*8+i)*64+ni*8+4];
            acc[i][0]+=v0.x; acc[i][1]+=v0.y; acc[i][2]+=v0.z; acc[i][3]+=v0.w;
            acc[i][4]+=v1.x; acc[i][5]+=v1.y; acc[i][6]+=v1.z; acc[i][7]+=v1.w;
        }
        float bb[8];
        #pragma unroll
        for (int j2=0;j2<8;++j2) bb[j2] = bias ? bias[n0+ni*8+j2] : 0.f;
        if (ksplit <= 1){
            #pragma unroll
            for (int i=0;i<8;++i){
                *(float4*)&C[(size_t)(m0+mi*8+i)*ldc + n0+ni*8]   =
                    make_float4(acc[i][0]+bb[0],acc[i][1]+bb[1],acc[i][2]+bb[2],acc[i][3]+bb[3]);
                *(float4*)&C[(size_t)(m0+mi*8+i)*ldc + n0+ni*8+4] =
                    make_float4(acc[i][4]+bb[4],acc[i][5]+bb[5],acc[i][6]+bb[6],acc[i][7]+bb[7]);
            }
        } else {
            #pragma unroll
            for (int i=0;i<8;++i)
                #pragma unroll
                for (int j2=0;j2<8;++j2)
                    atomicAdd(&C[(size_t)(m0+mi*8+i)*ldc + n0+ni*8+j2], acc[i][j2]+bb[j2]);
        }
    }
}

// NN batched: C[m][n] = sum_k A[m][k]*B[k][n], optional bn-relu fused on B columns.
// bhmode: z -> b=z>>2,h=z&3; B/C offset = b*sB + h*256 (attention PV addressing).
// ksplit>1 (non-bhmode): z = batch*ksplit + kz; atomicAdd into zeroed C.
__global__ __launch_bounds__(256) void gemm64_nn(
    const float* __restrict__ A, const float* __restrict__ Bm, float* __restrict__ C,
    int K, int lda, int ldb, int ldc, long sA, long sB, long sC,
    const float* __restrict__ bsc, const float* __restrict__ bsh, int bhmode, int ksplit)
{
    if (bhmode){
        int z = blockIdx.z;
        A  += (size_t)z*sA;
        Bm += (size_t)(z>>2)*sB + (size_t)(z&3)*256;
        C  += (size_t)(z>>2)*sC + (size_t)(z&3)*256;
    } else {
        int z = blockIdx.z;
        int bz = z, kz = 0;
        if (ksplit > 1){ bz = z / ksplit; kz = z % ksplit; }
        A  += (long)bz*sA + (size_t)kz*K;
        Bm += (long)bz*sB + (size_t)kz*K*ldb;
        C  += (long)bz*sC;
    }
    __shared__ float As[64][64], Bs[64][64];
    int t=threadIdx.x, w=t>>6, lane=t&63;
    int m0=blockIdx.y*64, n0=blockIdx.x*64;
    int mi=lane>>3, ni=lane&7;
    int kc=w*16;
    const float* Ar = A + (size_t)(m0+lane)*lda + kc;
    int kr = lane>>4, nc = (lane&15)*4;
    const float* Br = Bm + (size_t)(kc+kr)*ldb + n0 + nc;
    float4 sc4 = make_float4(1,1,1,1), sh4 = make_float4(0,0,0,0);
    if (bsc){ sc4 = *(const float4*)&bsc[n0+nc]; sh4 = *(const float4*)&bsh[n0+nc]; }
    float4 pa[4], pb[4];
    #pragma unroll
    for (int j=0;j<4;++j){
        pa[j]=*(const float4*)(Ar+j*4);
        pb[j]=*(const float4*)(Br + (size_t)(j*4)*ldb);
    }
    float acc[8][8] = {};
    for (int k0=0; k0<K; k0+=64){
        #pragma unroll
        for (int j=0;j<4;++j){
            As[kc+j*4+0][lane]=pa[j].x; As[kc+j*4+1][lane]=pa[j].y;
            As[kc+j*4+2][lane]=pa[j].z; As[kc+j*4+3][lane]=pa[j].w;
            float4 bv = pb[j];
            if (bsc){
                bv.x=fmaxf(bv.x*sc4.x+sh4.x,0.f); bv.y=fmaxf(bv.y*sc4.y+sh4.y,0.f);
                bv.z=fmaxf(bv.z*sc4.z+sh4.z,0.f); bv.w=fmaxf(bv.w*sc4.w+sh4.w,0.f);
            }
            *(float4*)&Bs[kc+kr+j*4][nc] = bv;
        }
        if (k0+64 < K){
            #pragma unroll
            for (int j=0;j<4;++j){
                pa[j]=*(const float4*)(Ar+k0+64+j*4);
                pb[j]=*(const float4*)(Br + (size_t)(k0+64+j*4)*ldb);
            }
        }
        #pragma unroll
        for (int kk=0; kk<16; ++kk){
            float4 a0=*(const float4*)&As[kc+kk][mi*8], a1=*(const float4*)&As[kc+kk][mi*8+4];
            float4 b0=*(const float4*)&Bs[kc+kk][ni*8], b1=*(const float4*)&Bs[kc+kk][ni*8+4];
            float am[8]={a0.x,a0.y,a0.z,a0.w,a1.x,a1.y,a1.z,a1.w};
            float bn[8]={b0.x,b0.y,b0.z,b0.w,b1.x,b1.y,b1.z,b1.w};
            #pragma unroll
            for (int i=0;i<8;++i)
                #pragma unroll
                for (int j2=0;j2<8;++j2) acc[i][j2] += am[i]*bn[j2];
        }
    }
    __syncthreads();
    float* s0 = &As[0][0]; float* s1 = &Bs[0][0];
    if (w>=2){
        float* d = (w==2)? s0 : s1;
        #pragma unroll
        for (int i=0;i<8;++i){
            *(float4*)&d[(mi*8+i)*64+ni*8]   = make_float4(acc[i][0],acc[i][1],acc[i][2],acc[i][3]);
            *(float4*)&d[(mi*8+i)*64+ni*8+4] = make_float4(acc[i][4],acc[i][5],acc[i][6],acc[i][7]);
        }
    }
    __syncthreads();
    if (w<2){
        const float* sv = (w==0)? s0 : s1;
        #pragma unroll
        for (int i=0;i<8;++i){
            float4 v0=*(const float4*)&sv[(mi*8+i)*64+ni*8];
            float4 v1=*(const float4*)&sv[(mi*8+i)*64+ni*8+4];
            acc[i][0]+=v0.x; acc[i][1]+=v0.y; acc[i][2]+=v0.z; acc[i][3]+=v0.w;
            acc[i][4]+=v1.x; acc[i][5]+=v1.y; acc[i][6]+=v1.z; acc[i][7]+=v1.w;
        }
    }
    __syncthreads();
    if (w==1){
        #pragma unroll
        for (int i=0;i<8;++i){
            *(float4*)&s0[(mi*8+i)*64+ni*8]   = make_float4(acc[i][0],acc[i][1],acc[i][2],acc[i][3]);
            *(float4*)&s0[(mi*8+i)*64+ni*8+4] = make_float4(acc[i][4],acc[i][5],acc[i][6],acc[i][7]);
        }
    }
    __syncthreads();
    if (w==0){
        #pragma unroll
        for (int i=0;i<8;++i){
            float4 v0=*(const float4*)&s0[(mi*8+i)*64+ni*8];
            float4 v1=*(const float4*)&s0[(mi*8+i)*64+ni*8+4];
            acc[i][0]+=v0.x; acc[i][1]+=v0.y; acc[i][2]+=v0.z; acc[i][3]+=v0.w;
            acc[i][4]+=v1.x; acc[i][5]+=v1.y; acc[i][6]+=v1.z; acc[i][7]+=v1.w;
        }
        if (ksplit <= 1){
            #pragma unroll
            for (int i=0;i<8;++i){
                *(float4*)&C[(size_t)(m0+mi*8+i)*ldc + n0+ni*8]   =
                    make_float4(acc[i][0],acc[i][1],acc[i][2],acc[i][3]);
                *(float4*)&C[(size_t)(m0+mi*8+i)*ldc + n0+ni*8+4] =
                    make_float4(acc[i][4],acc[i][5],acc[i][6],acc[i][7]);
            }
        } else {
            #pragma unroll
            for (int i=0;i<8;++i)
                #pragma unroll
                for (int j2=0;j2<8;++j2)
                    atomicAdd(&C[(size_t)(m0+mi*8+i)*ldc + n0+ni*8+j2], acc[i][j2]);
        }
    }
}

// ---------------- PJ (1024x256) -> pjT[b][a][n] transpose via LDS ----------------
__global__ void transp_v15(const float* __restrict__ PJ, float* __restrict__ pjT){
    __shared__ float T[64][68];
    int b = blockIdx.z;
    int a0 = blockIdx.x*64, n0 = blockIdx.y*64;
    int t = threadIdx.x;
    int c = t&15, r = t>>4;
    for (int rr=r; rr<64; rr+=16){
        float4 v = *(const float4*)&PJ[(size_t)(b*512+n0+rr)*256 + a0 + c*4];
        T[rr][c*4]=v.x; T[rr][c*4+1]=v.y; T[rr][c*4+2]=v.z; T[rr][c*4+3]=v.w;
    }
    __syncthreads();
    for (int rr=r; rr<64; rr+=16){
        float4 o = make_float4(T[c*4][rr], T[c*4+1][rr], T[c*4+2][rr], T[c*4+3][rr]);
        *(float4*)&pjT[(size_t)b*131072 + (size_t)(a0+rr)*512 + n0 + c*4] = o;
    }
}

// ---------------- parallel batchnorm stats: stage1 (64 rows x 64 feats per block) ------
__global__ void bnp1(const float* __restrict__ src, float* __restrict__ PS,
                     float* __restrict__ PS2, int F){
    int f0 = blockIdx.x*64, r0 = blockIdx.y*64;
    int fi = threadIdx.x & 63, rg = threadIdx.x >> 6;
    float s=0.f, s2=0.f;
    #pragma unroll
    for (int i=0;i<16;++i){
        float v = src[(size_t)(r0+rg+i*4)*F + f0+fi];
        s += v; s2 += v*v;
    }
    __shared__ float ls[4][64], ls2[4][64];
    ls[rg][fi]=s; ls2[rg][fi]=s2; __syncthreads();
    if (rg==0){
        PS [blockIdx.y*F + f0+fi] = ls[0][fi]+ls[1][fi]+ls[2][fi]+ls[3][fi];
        PS2[blockIdx.y*F + f0+fi] = ls2[0][fi]+ls2[1][fi]+ls2[2][fi]+ls2[3][fi];
    }
}

// ---------------- stage2: fold 16 chunks, produce scale/shift ----------------
__global__ void bnp2(const float* __restrict__ PS, const float* __restrict__ PS2,
                     const float* __restrict__ g, const float* __restrict__ be,
                     float* __restrict__ scale, float* __restrict__ shift, int F){
    int f = blockIdx.x*64 + threadIdx.x;
    float S=0.f, S2=0.f;
    #pragma unroll
    for (int c=0;c<16;++c){ S += PS[c*F+f]; S2 += PS2[c*F+f]; }
    float m  = S*(1.f/1024.f);
    float var = S2*(1.f/1024.f) - m*m;
    float sc = g[f] * rsqrtf(var + 1e-5f);
    scale[f]=sc; shift[f]=be[f] - m*sc;
}

// ---------------- parallel bn2+relu+mean: stage1 (64 rows per block) ----------------
__global__ void feat_p(const float* __restrict__ h4, const float* __restrict__ sc,
                       const float* __restrict__ sh, float* __restrict__ featp){
    int b = blockIdx.x, chunk = blockIdx.y;
    int t = threadIdx.x;              // 128
    float s = sc[t], o = sh[t], acc = 0.f;
    int n0 = chunk*64;
    #pragma unroll
    for (int i=0;i<64;++i){
        float v = h4[(size_t)(b*512+n0+i)*128 + t]*s + o;
        acc += fmaxf(v, 0.f);
    }
    featp[(b*8+chunk)*128 + t] = acc;
}

__global__ void feat_f(const float* __restrict__ featp, float* __restrict__ feat){
    int b = blockIdx.x, t = threadIdx.x;
    float a = 0.f;
    #pragma unroll
    for (int c=0;c<8;++c) a += featp[(b*8+c)*128 + t];
    feat[b*128+t] = a*(1.f/512.f);
}

// ================= legacy kernels (fallback non-ws path) =================
__global__ void gemm_nn32(const float* __restrict__ A, const float* __restrict__ Bm,
                          float* __restrict__ C, int K, int lda, int ldb, int ldc,
                          long sA, long sB, long sC,
                          const float* __restrict__ bsc, const float* __restrict__ bsh){
    A  += (long)blockIdx.z * sA;
    Bm += (long)blockIdx.z * sB;
    C  += (long)blockIdx.z * sC;
    __shared__ float As[16][32], Bs[16][64];
    int n0 = blockIdx.x*64, m0 = blockIdx.y*32;
    int t = threadIdx.x, tx = t & 15, ty = t >> 4;
    int sr = t >> 3, sk = (t & 7)*2;
    int bk = t >> 4, bn4 = (t & 15)*4;
    float acc[2][4] = {};
    for (int k0=0; k0<K; k0+=16){
        #pragma unroll
        for (int i=0;i<2;++i) As[sk+i][sr] = A[(size_t)(m0+sr)*lda + k0+sk+i];
        float4 bv = *(const float4*)&Bm[(size_t)(k0+bk)*ldb + n0+bn4];
        if (bsc){
            bv.x = fmaxf(bv.x*bsc[n0+bn4+0]+bsh[n0+bn4+0], 0.f);
            bv.y = fmaxf(bv.y*bsc[n0+bn4+1]+bsh[n0+bn4+1], 0.f);
            bv.z = fmaxf(bv.z*bsc[n0+bn4+2]+bsh[n0+bn4+2], 0.f);
            bv.w = fmaxf(bv.w*bsc[n0+bn4+3]+bsh[n0+bn4+3], 0.f);
        }
        *(float4*)&Bs[bk][bn4] = bv;
        __syncthreads();
        #pragma unroll
        for (int k=0;k<16;++k){
            float a0 = As[k][ty*2], a1 = As[k][ty*2+1];
            float4 b = *(const float4*)&Bs[k][tx*4];
            acc[0][0]+=a0*b.x; acc[0][1]+=a0*b.y; acc[0][2]+=a0*b.z; acc[0][3]+=a0*b.w;
            acc[1][0]+=a1*b.x; acc[1][1]+=a1*b.y; acc[1][2]+=a1*b.z; acc[1][3]+=a1*b.w;
        }
        __syncthreads();
    }
    #pragma unroll
    for (int i=0;i<2;++i){
        float4 v = make_float4(acc[i][0],acc[i][1],acc[i][2],acc[i][3]);
        *(float4*)&C[(size_t)(m0+ty*2+i)*ldc + n0+tx*4] = v;
    }
}

__global__ void gemm_nt32(const float* __restrict__ A, const float* __restrict__ Bm,
                          float* __restrict__ C, int K, int lda, int ldb, int ldc,
                          const float* __restrict__ bias){
    __shared__ float As[16][32], Bs[16][64];
    int n0 = blockIdx.x*64, m0 = blockIdx.y*32;
    int t = threadIdx.x, tx = t & 15, ty = t >> 4;
    int sr = t >> 3, sk = (t & 7)*2;
    int bn = t >> 2, bkk = (t & 3)*4;         // B^T staging: row bn, 4 k's
    float acc[2][4] = {};
    for (int k0=0; k0<K; k0+=16){
        #pragma unroll
        for (int i=0;i<2;++i) As[sk+i][sr] = A[(size_t)(m0+sr)*lda + k0+sk+i];
        float4 wv = *(const float4*)&Bm[(size_t)(n0+bn)*ldb + k0+bkk];
        Bs[bkk+0][bn]=wv.x; Bs[bkk+1][bn]=wv.y; Bs[bkk+2][bn]=wv.z; Bs[bkk+3][bn]=wv.w;
        __syncthreads();
        #pragma unroll
        for (int k=0;k<16;++k){
            float a0 = As[k][ty*2], a1 = As[k][ty*2+1];
            float4 b = *(const float4*)&Bs[k][tx*4];
            acc[0][0]+=a0*b.x; acc[0][1]+=a0*b.y; acc[0][2]+=a0*b.z; acc[0][3]+=a0*b.w;
            acc[1][0]+=a1*b.x; acc[1][1]+=a1*b.y; acc[1][2]+=a1*b.z; acc[1][3]+=a1*b.w;
        }
        __syncthreads();
    }
    float4 bb = bias ? *(const float4*)&bias[n0+tx*4] : make_float4(0,0,0,0);
    #pragma unroll
    for (int i=0;i<2;++i){
        float4 v = make_float4(acc[i][0]+bb.x,acc[i][1]+bb.y,acc[i][2]+bb.z,acc[i][3]+bb.w);
        *(float4*)&C[(size_t)(m0+ty*2+i)*ldc + n0+tx*4] = v;
    }
}

__global__ void gemm_x_v12(const float* __restrict__ X, const float* __restrict__ Wg,
                           float* __restrict__ dst){
    __shared__ float xs[4][1024];
    int m0 = blockIdx.x*4;
    int t = threadIdx.x;
    for (int i=t;i<4096;i+=256){ int r=i>>10, c=i&1023; xs[r][c]=X[(size_t)(m0+r)*1024+c]; }
    __syncthreads();
    const float* w0 = Wg + (size_t)(t*4)*1024;
    float acc[4][4] = {};
    for (int k0=0;k0<1024;k0+=16){
        float4 xv[4][4];
        #pragma unroll
        for (int r=0;r<4;++r)
            #pragma unroll
            for (int c=0;c<4;++c) xv[r][c] = *(const float4*)&xs[r][k0+4*c];
        #pragma unroll
        for (int j=0;j<4;++j){
            const float* wr = w0 + (size_t)j*1024 + k0;
            #pragma unroll
            for (int c=0;c<4;++c){
                float4 w = *(const float4*)(wr + 4*c);
                #pragma unroll
                for (int r=0;r<4;++r)
                    acc[r][j] += xv[r][c].x*w.x + xv[r][c].y*w.y
                               + xv[r][c].z*w.z + xv[r][c].w*w.w;
            }
        }
    }
    int n0 = t*4;
    #pragma unroll
    for (int r=0;r<4;++r){
        float4 v = make_float4(acc[r][0],acc[r][1],acc[r][2],acc[r][3]);
        *(float4*)&dst[(size_t)(m0+r)*1024 + n0] = v;
    }
}

__global__ void attn_v12(const float* __restrict__ hp, const float* __restrict__ attn,
                         float* __restrict__ nf){
    int blk = blockIdx.x;
    int bh = blk >> 6, i0 = (blk & 63)*8;
    int b = bh >> 2, h = bh & 3;
    int t = threadIdx.x;
    __shared__ float ais[256], ajs[256], sjs[512], sis[8], inv[8];
    __shared__ float alpha[8][512];
    __shared__ float red[256];
    ais[t] = attn[h*512 + t];
    ajs[t] = attn[h*512 + 256 + t];
    __syncthreads();
    const float* hpb = hp + (size_t)b*524288 + h*256;
    for (int j=t; j<512; j+=256){
        const float* row = hpb + (size_t)j*1024;
        float s=0.f;
        for (int d=0; d<256; ++d) s += row[d]*ajs[d];
        sjs[j]=s;
    }
    if (t<8){
        const float* row = hpb + (size_t)(i0+t)*1024;
        float s=0.f;
        for (int d=0; d<256; ++d) s += row[d]*ais[d];
        sis[t]=s;
    }
    __syncthreads();
    for (int ii=0; ii<8; ++ii){
        float si = sis[ii];
        float e0 = si + sjs[t], e1 = si + sjs[t+256];
        e0 = (e0>=0.f)? e0 : 0.2f*e0;
        e1 = (e1>=0.f)? e1 : 0.2f*e1;
        float p0 = expf(e0), p1 = expf(e1);
        alpha[ii][t]=p0; alpha[ii][t+256]=p1;
        red[t]=p0+p1; __syncthreads();
        for (int s=128; s>0; s>>=1){ if (t<s) red[t]+=red[t+s]; __syncthreads(); }
        if (t==0) inv[ii] = 1.0f/red[0];
        __syncthreads();
    }
    float acc[8] = {};
    for (int j=0; j<512; ++j){
        float r = hpb[(size_t)j*1024 + t];
        #pragma unroll
        for (int ii=0; ii<8; ++ii) acc[ii] += alpha[ii][j]*r;
    }
    #pragma unroll
    for (int ii=0; ii<8; ++ii)
        nf[(size_t)(b*512+i0+ii)*1024 + h*256 + t] = acc[ii]*inv[ii];
}

// ---------------- s_i / s_j precompute ----------------
__global__ void sij_v14(const float* __restrict__ hp, const float* __restrict__ attn,
                        float* __restrict__ SI, float* __restrict__ SJ){
    int t = threadIdx.x;
    int lane = t & 63, w = t >> 6;
    int h  = lane >> 4;
    int e0 = (lane & 15) * 16;
    const float* ai = attn + h*512 + e0;
    const float* aj = ai + 256;
    float4 wi[4], wj[4];
    #pragma unroll
    for (int q=0;q<4;++q){ wi[q] = *(const float4*)(ai + 4*q); wj[q] = *(const float4*)(aj + 4*q); }
    int row0 = blockIdx.x*16 + w*4;
    for (int r=0;r<4;++r){
        int row = row0 + r;
        const float* hr = hp + (size_t)row*1024 + h*256 + e0;
        float si=0.f, sj=0.f;
        #pragma unroll
        for (int q=0;q<4;++q){
            float4 v = *(const float4*)(hr + 4*q);
            si += v.x*wi[q].x + v.y*wi[q].y + v.z*wi[q].z + v.w*wi[q].w;
            sj += v.x*wj[q].x + v.y*wj[q].y + v.z*wj[q].z + v.w*wj[q].w;
        }
        #pragma unroll
        for (int s=1;s<16;s<<=1){
            si += __shfl_xor(si, s, 64);
            sj += __shfl_xor(sj, s, 64);
        }
        if ((lane & 15)==0){
            int b = row >> 9, n = row & 511;
            SI[(size_t)(b*4+h)*512 + n] = si;
            SJ[(size_t)(b*4+h)*512 + n] = sj;
        }
    }
}

// ---------------- alpha materialization: exp(leaky(si+sj))*inv -> ALP[bh][i][j] --------
__global__ __launch_bounds__(512) void asm_v17(const float* __restrict__ SI,
                                               const float* __restrict__ SJ,
                                               float* __restrict__ ALP){
    int blk = blockIdx.x;                 // 256 blocks
    int bh = blk >> 5, i0 = (blk & 31)*16;
    int t = threadIdx.x;                  // 512 = all j
    int w = t >> 6, lane = t & 63;
    __shared__ float wsum[8][16];
    __shared__ float inv[16];
    float sj = SJ[(size_t)bh*512 + t];
    const float* sip = SI + (size_t)bh*512 + i0;
    float p[16], part[16];
    #pragma unroll
    for (int ii=0; ii<16; ++ii){
        float e = sip[ii] + sj;
        e = (e>=0.f)? e : 0.2f*e;
        p[ii] = expf(e);
        part[ii] = p[ii];
    }
    #pragma unroll
    for (int s=1;s<64;s<<=1){
        #pragma unroll
        for (int ii=0;ii<16;++ii) part[ii] += __shfl_xor(part[ii], s, 64);
    }
    if (lane==0){
        #pragma unroll
        for (int ii=0;ii<16;++ii) wsum[w][ii] = part[ii];
    }
    __syncthreads();
    if (t<16){
        float s=0.f;
        #pragma unroll
        for (int ww=0;ww<8;++ww) s += wsum[ww][t];
        inv[t] = 1.0f/s;
    }
    __syncthreads();
    float* dst = ALP + (size_t)bh*262144 + (size_t)i0*512 + t;
    #pragma unroll
    for (int ii=0; ii<16; ++ii)
        dst[(size_t)ii*512] = p[ii]*inv[ii];
}

// ---------------- legacy pipj (fallback path) ----------------
__global__ void pipj_v13(const float* __restrict__ nf, const float* __restrict__ W1,
                         const float* __restrict__ b1, float* __restrict__ pi,
                         float* __restrict__ pjT){
    int half = blockIdx.z >> 5;
    int m0 = (blockIdx.z & 31)*32;
    int a0 = blockIdx.x*64;
    __shared__ float As[16][32], Bs[16][64];
    int t = threadIdx.x, tx = t & 15, ty = t >> 4;
    int sr = t >> 3, sk = (t & 7)*2;
    int bn = t >> 2, bkk = (t & 3)*4;
    const float* Wbase = W1 + (half ? 1024 : 0);
    float acc[2][4] = {};
    for (int k0=0; k0<1024; k0+=16){
        #pragma unroll
        for (int i=0;i<2;++i) As[sk+i][sr] = nf[(size_t)(m0+sr)*1024 + k0+sk+i];
        float4 wv = *(const float4*)&Wbase[(size_t)(a0+bn)*2048 + k0+bkk];
        Bs[bkk+0][bn]=wv.x; Bs[bkk+1][bn]=wv.y; Bs[bkk+2][bn]=wv.z; Bs[bkk+3][bn]=wv.w;
        __syncthreads();
        #pragma unroll
        for (int k=0;k<16;++k){
            float a0v = As[k][ty*2], a1v = As[k][ty*2+1];
            float4 b = *(const float4*)&Bs[k][tx*4];
            acc[0][0]+=a0v*b.x; acc[0][1]+=a0v*b.y; acc[0][2]+=a0v*b.z; acc[0][3]+=a0v*b.w;
            acc[1][0]+=a1v*b.x; acc[1][1]+=a1v*b.y; acc[1][2]+=a1v*b.z; acc[1][3]+=a1v*b.w;
        }
        __syncthreads();
    }
    if (!half){
        float4 bb = *(const float4*)&b1[a0+tx*4];
        #pragma unroll
        for (int i=0;i<2;++i){
            float4 v = make_float4(acc[i][0]+bb.x,acc[i][1]+bb.y,acc[i][2]+bb.z,acc[i][3]+bb.w);
            *(float4*)&pi[(size_t)(m0+ty*2+i)*256 + a0+tx*4] = v;
        }
    } else {
        #pragma unroll
        for (int i=0;i<2;++i){
            int m = m0+ty*2+i;
            size_t base = (size_t)(m>>9)*131072 + (m&511);
            #pragma unroll
            for (int j=0;j<4;++j)
                pjT[base + (size_t)(a0+tx*4+j)*512] = acc[i][j];
        }
    }
}

// ---------------- edge scores ----------------
__global__ void edge_v10(const float* __restrict__ pi, const float* __restrict__ pjT,
                         const float* __restrict__ w2, const float* __restrict__ b2,
                         float* __restrict__ es){
    int blk = blockIdx.x;
    int b = blk >> 8, i0 = (blk & 255)*2;
    int t = threadIdx.x;
    __shared__ float pis[2][256], w2s[256];
    w2s[t] = w2[t];
    pis[0][t] = pi[(size_t)(b*512+i0)*256 + t];
    pis[1][t] = pi[(size_t)(b*512+i0+1)*256 + t];
    __syncthreads();
    float a00=0,a01=0,a10=0,a11=0;
    const float* pj = pjT + (size_t)b*131072;
    for (int a=0; a<256; ++a){
        float pv0 = pj[(size_t)a*512 + t];
        float pv1 = pj[(size_t)a*512 + t + 256];
        float w  = w2s[a];
        a00 += fmaxf(pis[0][a]+pv0, 0.f)*w;
        a01 += fmaxf(pis[0][a]+pv1, 0.f)*w;
        a10 += fmaxf(pis[1][a]+pv0, 0.f)*w;
        a11 += fmaxf(pis[1][a]+pv1, 0.f)*w;
    }
    float b2f = b2[0];
    es[(size_t)(b*512+i0+0)*512 + t]       = a00 + b2f;
    es[(size_t)(b*512+i0+0)*512 + t + 256] = a01 + b2f;
    es[(size_t)(b*512+i0+1)*512 + t]       = a10 + b2f;
    es[(size_t)(b*512+i0+1)*512 + t + 256] = a11 + b2f;
}

// ---------------- exp(2*es) in place + sum ----------------
__global__ void k_exp_v13(float* __restrict__ u, float* __restrict__ S){
    int b = blockIdx.x >> 8;
    size_t base = (size_t)b*262144 + (size_t)(blockIdx.x & 255)*1024;
    int t = threadIdx.x;
    float acc = 0.f;
    for (int i=t;i<1024;i+=256){ float v = expf(u[base+i]*2.0f); u[base+i]=v; acc+=v; }
    __shared__ float red[256];
    red[t]=acc; __syncthreads();
    for (int s=128;s>0;s>>=1){ if(t<s) red[t]+=red[t+s]; __syncthreads(); }
    if (t==0) atomicAdd(&S[b], red[0]);
}

// ---------------- parallel radix histogram ----------------
__global__ void k_hist_v11(const float* __restrict__ u, unsigned* __restrict__ hist,
                           const unsigned* __restrict__ pfx, int cmpShift, int shift,
                           unsigned mask, int nbins){
    __shared__ unsigned h[2048];
    for (int i=threadIdx.x;i<nbins;i+=256) h[i]=0;
    __syncthreads();
    int b = blockIdx.x>>6;
    size_t base = (size_t)b*262144 + (size_t)(blockIdx.x&63)*4096;
    unsigned p = pfx ? pfx[b] : 0u;
    for (int i=threadIdx.x;i<4096;i+=256){
        unsigned bits = __float_as_uint(u[base+i]);
        if (!pfx || (bits>>cmpShift)==p) atomicAdd(&h[(bits>>shift)&mask],1u);
    }
    __syncthreads();
    for (int i=threadIdx.x;i<nbins;i+=256) if (h[i]) atomicAdd(&hist[b*nbins+i], h[i]);
}

// ---------------- scan histogram, descend one level ----------------
__global__ void k_scan_v11(const unsigned* __restrict__ hist, int nbins,
                           unsigned* __restrict__ pfx, unsigned* __restrict__ rank,
                           int passBits, int first, float* __restrict__ thrOut){
    __shared__ unsigned part[2][256];
    int batch = threadIdx.x>>8, lane = threadIdx.x&255;
    int chunk = nbins/256;
    const unsigned* hb = hist + batch*nbins;
    unsigned s=0;
    for (int i=0;i<chunk;++i) s += hb[lane*chunk+i];
    part[batch][lane]=s;
    __syncthreads();
    if (lane==0){
        unsigned r = first ? 52429u : rank[batch];
        unsigned cum=0; int c=0;
        for (;c<256;++c){ unsigned pc=part[batch][c]; if (cum+pc>r) break; cum+=pc; }
        if (c==256) c=255;
        int bin=c*chunk;
        for (int i=0;i<chunk;++i){ unsigned cnt=hb[c*chunk+i]; if (cum+cnt>r){ bin=c*chunk+i; break;} cum+=cnt; }
        rank[batch]=r-cum;
        unsigned np = ((first?0u:pfx[batch])<<passBits) | (unsigned)bin;
        pfx[batch]=np;
        if (thrOut) thrOut[batch]=__uint_as_float(np);
    }
}

// ---------------- parallel kept-sum/count ----------------
__global__ void k_csum_v11(const float* __restrict__ u, const float* __restrict__ THR,
                           float* __restrict__ CS, unsigned* __restrict__ KC){
    int b = blockIdx.x>>6;
    size_t base = (size_t)b*262144 + (size_t)(blockIdx.x&63)*4096;
    float th = THR[b];
    float cs=0.f; unsigned kc=0;
    for (int i=threadIdx.x;i<4096;i+=256){ float v=u[base+i]; if (v>=th){ cs+=v; kc++; } }
    __shared__ float rf[256]; __shared__ unsigned ru[256];
    rf[threadIdx.x]=cs; ru[threadIdx.x]=kc; __syncthreads();
    for (int s=128;s>0;s>>=1){ if(threadIdx.x<s){ rf[threadIdx.x]+=rf[threadIdx.x+s]; ru[threadIdx.x]+=ru[threadIdx.x+s]; } __syncthreads(); }
    if (threadIdx.x==0){ atomicAdd(&CS[b], rf[0]); atomicAdd(&KC[b], ru[0]); }
}

// ---------------- finalize thr/dinv ----------------
__global__ void k_fin_v11(const float* __restrict__ S, const float* __restrict__ CS,
                          const unsigned* __restrict__ KC, float* __restrict__ THR,
                          float* __restrict__ DINV){
    int t = threadIdx.x;
    if (t < 2){
        float ks = CS[t]; float th = THR[t];
        if (KC[t] < 209715u){ th = 0.f; ks = S[t]; }
        THR[t]=th;
        DINV[t]=1.0f/(ks + 1e-12f*S[t]);
    }
}

// ---------------- adjacency, in place over u ----------------
__global__ void adj_v10(float* __restrict__ u, const float* __restrict__ thrU,
                        const float* __restrict__ dinv){
    int idx = blockIdx.x*256 + threadIdx.x;
    int b = idx >> 18;
    float v = u[idx];
    u[idx] = (v >= thrU[b]) ? v*dinv[b] : 0.0f;
}

// ---------------- legacy batchnorm stats (fallback path) ----------------
__global__ void bnstats_v10(const float* __restrict__ src, const float* __restrict__ g,
                            const float* __restrict__ be, float* __restrict__ scale,
                            float* __restrict__ shift, int F){
    int f0 = blockIdx.x*64;
    int fi = threadIdx.x & 63, rg = threadIdx.x >> 6;
    float s=0.f, s2=0.f;
    for (int r=rg; r<1024; r+=4){ float v = src[(size_t)r*F + f0+fi]; s+=v; s2+=v*v; }
    __shared__ float ls[4][64], ls2[4][64];
    ls[rg][fi]=s; ls2[rg][fi]=s2; __syncthreads();
    if (rg==0){
        float Sv = ls[0][fi]+ls[1][fi]+ls[2][fi]+ls[3][fi];
        float S2 = ls2[0][fi]+ls2[1][fi]+ls2[2][fi]+ls2[3][fi];
        float m  = Sv*(1.f/1024.f);
        float var = S2*(1.f/1024.f) - m*m;
        float sc = g[f0+fi] * rsqrtf(var + 1e-5f);
        scale[f0+fi]=sc;
        shift[f0+fi]=be[f0+fi] - m*sc;
    }
}

// ---------------- legacy bn2 + relu + mean over N (fallback path) ----------------
__global__ void feat_v10(const float* __restrict__ h4, const float* __restrict__ sc,
                         const float* __restrict__ sh, float* __restrict__ feat){
    int b = blockIdx.x, t = threadIdx.x;
    float s = sc[t], o = sh[t], acc = 0.f;
    for (int n=0; n<512; ++n){
        float v = h4[(size_t)(b*512+n)*128 + t]*s + o;
        acc += fmaxf(v, 0.f);
    }
    feat[b*128+t] = acc*(1.f/512.f);
}

// ---------------- classifier ----------------
__global__ void cls_v10(const float* __restrict__ feat, const float* __restrict__ cls_w,
                        const float* __restrict__ cls_b, float* __restrict__ out){
    int t = threadIdx.x;
    if (t < 20){
        int b = t/10, c = t%10;
        float acc = cls_b[c];
        for (int o=0; o<128; ++o)
            acc += feat[b*128+o]*cls_w[c*128+o];
        out[t] = acc;
    }
}

// ---------------- launch ----------------
extern "C" void kernel_launch(void* const* d_in, const int* in_sizes, int n_in,
                              void* d_out, int out_size, void* d_ws, size_t ws_size,
                              hipStream_t stream){
    (void)in_sizes; (void)n_in; (void)out_size;
    const float* x     = (const float*)d_in[0];
    const float* Wg    = (const float*)d_in[1];
    const float* attn  = (const float*)d_in[2];
    const float* W1    = (const float*)d_in[3];
    const float* b1    = (const float*)d_in[4];
    const float* w2    = (const float*)d_in[5];
    const float* b2    = (const float*)d_in[6];
    const float* gc1_w = (const float*)d_in[7];
    const float* gc1_b = (const float*)d_in[8];
    const float* bn1_g = (const float*)d_in[9];
    const float* bn1_b = (const float*)d_in[10];
    const float* gc2_w = (const float*)d_in[11];
    const float* gc2_b = (const float*)d_in[12];
    const float* bn2_g = (const float*)d_in[13];
    const float* bn2_b = (const float*)d_in[14];
    const float* cls_w = (const float*)d_in[15];
    const float* cls_b = (const float*)d_in[16];
    float* out = (float*)d_out;

    float *HP, *NF, *U, *PI, *PJT, *H1, *H2, *H3, *H4;
    float *STAT, *BN1S, *BN1H, *BN2S, *BN2H, *FEAT;
    float *SIbuf = nullptr, *SJbuf = nullptr, *PJ = nullptr, *ALP = nullptr;
    float *PSb = nullptr, *PS2b = nullptr, *FEATP = nullptr;
    int wsPath = (ws_size >= (size_t)22*1024*1024);

    if (wsPath){
        float* W = (float*)d_ws;
        HP  = W + 0;        NF  = W + 1048576;  H1 = W + 2097152;
        PI  = W + 3145728;  PJT = W + 3407872;  U  = W + 3670016;
        H2  = W + 4194304;  H3  = W + 4718592;  H4 = W + 5242880;
        BN1S= W + 5374208;  BN1H= W + 5374720;
        BN2S= W + 5375232;  BN2H= W + 5375360;  FEAT = W + 5375488;
        STAT= W + 5400000;
        SIbuf = W + 5500000; SJbuf = W + 5504096;
        PJ  = H2;            // H2 region free until gc1 GEMM; PJ dead by then
        ALP = PI;            // 2,097,152 floats spanning PI..H3 — dead before pipj writes PI
        PSb = W + 5420000; PS2b = W + 5430000; FEATP = W + 5440000;
    } else {
        HP  = (float*)x;
        NF  = (float*)Wg;
        PI  = (float*)x;
        PJT = (float*)x + 262144;
        U   = (float*)W1;
        H1  = (float*)x;
        H2  = (float*)Wg;
        H3  = (float*)gc1_w;
        H4  = (float*)x;
        STAT= (float*)x;
        float* A = (float*)attn;
        BN1S = A+8;    BN1H = A+520;
        BN2S = A+1032; BN2H = A+1160;  FEAT = A+1288;
    }
    float*    S    = STAT+2;
    float*    CS   = STAT+4;
    unsigned* KC   = (unsigned*)(STAT+6);
    unsigned* PFX  = (unsigned*)(STAT+8);
    unsigned* RANK = (unsigned*)(STAT+10);
    float*    THR  = STAT+12;
    float*    DINV = STAT+14;
    unsigned* H0   = (unsigned*)(STAT+16);
    unsigned* Hh1  = (unsigned*)(STAT+16+4096);
    unsigned* Hh2  = (unsigned*)(STAT+16+8192);

    if (wsPath){
        hipMemsetAsync(HP, 0, (size_t)1048576*sizeof(float), stream);
        gemm64_nt<<<dim3(16,16,2),256,0,stream>>>(x, Wg, HP, 512, 1024, 1024, 1024,
                                                  nullptr, nullptr, nullptr, nullptr, 2);
        sij_v14 <<<64,256,0,stream>>>(HP, attn, SIbuf, SJbuf);
        asm_v17 <<<256,512,0,stream>>>(SIbuf, SJbuf, ALP);
        // PV as batched GEMM: nf[bh] = ALP[bh] @ hp[bh]  (bhmode addressing)
        gemm64_nn<<<dim3(4,8,8),256,0,stream>>>(ALP, HP, NF, 512, 512, 1024, 1024,
                                                262144, 524288, 524288, nullptr, nullptr, 1, 1);
        // ALP consumed; zero PI/PJ for ksplit-atomic pipj
        hipMemsetAsync(PI, 0, (size_t)262144*sizeof(float), stream);
        hipMemsetAsync(PJ, 0, (size_t)262144*sizeof(float), stream);
        // pi = nf@W1i^T + b1 ; PJ = nf@W1j^T; z = sel*2 + kz (ksplit=2)
        gemm64_nt<<<dim3(4,16,4),256,0,stream>>>(NF, W1, PI, 512, 1024, 2048, 256,
                                                 b1, W1+1024, PJ, nullptr, 2);
        transp_v15<<<dim3(4,8,2),256,0,stream>>>(PJ, PJT);
    } else {
        gemm_x_v12<<<256,256,0,stream>>>(x, Wg, HP);
        attn_v12  <<<512,256,0,stream>>>(HP, attn, NF);
        pipj_v13  <<<dim3(4,1,64),256,0,stream>>>(NF, W1, b1, PI, PJT);
    }
    edge_v10  <<<512,256,0,stream>>>(PI, PJT, w2, b2, U);
    hipMemsetAsync(STAT, 0, 10256*sizeof(float), stream);
    if (wsPath) hipMemsetAsync(H4, 0, (size_t)131072*sizeof(float), stream);
    k_exp_v13 <<<512,256,0,stream>>>(U, S);
    k_hist_v11<<<128,256,0,stream>>>(U, H0, nullptr, 0, 21, 0x7FFu, 2048);
    k_scan_v11<<<1,512,0,stream>>>(H0, 2048, PFX, RANK, 11, 1, nullptr);
    k_hist_v11<<<128,256,0,stream>>>(U, Hh1, PFX, 21, 10, 0x7FFu, 2048);
    k_scan_v11<<<1,512,0,stream>>>(Hh1, 2048, PFX, RANK, 11, 0, nullptr);
    k_hist_v11<<<128,256,0,stream>>>(U, Hh2, PFX, 10, 0, 0x3FFu, 1024);
    k_scan_v11<<<1,512,0,stream>>>(Hh2, 1024, PFX, RANK, 10, 0, THR);
    k_csum_v11<<<128,256,0,stream>>>(U, THR, CS, KC);
    k_fin_v11 <<<1,64,0,stream>>>(S, CS, KC, THR, DINV);
    adj_v10   <<<2048,256,0,stream>>>(U, THR, DINV);           // U now holds adj

    if (wsPath){
        hipMemsetAsync(H1, 0, (size_t)1048576*sizeof(float), stream);
        gemm64_nn<<<dim3(16,8,4),256,0,stream>>>(U, NF, H1, 256, 512, 1024, 1024,
                                                 262144, 524288, 524288, nullptr, nullptr, 0, 2);
        hipMemsetAsync(H2, 0, (size_t)524288*sizeof(float), stream);
        gemm64_nt<<<dim3(8,16,2),256,0,stream>>>(H1, gc1_w, H2, 512, 1024, 1024, 512,
                                                 gc1_b, nullptr, nullptr, nullptr, 2);
        bnp1<<<dim3(8,16),256,0,stream>>>(H2, PSb, PS2b, 512);
        bnp2<<<8,64,0,stream>>>(PSb, PS2b, bn1_g, bn1_b, BN1S, BN1H, 512);
        hipMemsetAsync(H3, 0, (size_t)524288*sizeof(float), stream);
        gemm64_nn<<<dim3(8,8,4),256,0,stream>>>(U, H2, H3, 256, 512, 512, 512,
                                                262144, 262144, 262144, BN1S, BN1H, 0, 2);
        // split-K=4 over zeroed H4, atomicAdd epilogue (bias from kz==0)
        gemm64_nt<<<dim3(2,16,4),256,0,stream>>>(H3, gc2_w, H4, 128, 512, 512, 128,
                                                 gc2_b, nullptr, nullptr, nullptr, 4);
        bnp1<<<dim3(2,16),256,0,stream>>>(H4, PSb, PS2b, 128);
        bnp2<<<2,64,0,stream>>>(PSb, PS2b, bn2_g, bn2_b, BN2S, BN2H, 128);
        feat_p<<<dim3(2,8),128,0,stream>>>(H4, BN2S, BN2H, FEATP);
        feat_f<<<2,128,0,stream>>>(FEATP, FEAT);
    } else {
        gemm_nn32 <<<dim3(16,16,2),256,0,stream>>>(U, NF, H1, 512, 512, 1024, 1024,
                                                   262144, 524288, 524288, nullptr, nullptr);
        gemm_nt32 <<<dim3(8,32),256,0,stream>>>(H1, gc1_w, H2, 1024, 1024, 1024, 512, gc1_b);
        bnstats_v10<<<8,256,0,stream>>>(H2, bn1_g, bn1_b, BN1S, BN1H, 512);
        gemm_nn32 <<<dim3(8,16,2),256,0,stream>>>(U, H2, H3, 512, 512, 512, 512,
                                                  262144, 262144, 262144, BN1S, BN1H);
        gemm_nt32 <<<dim3(2,32),256,0,stream>>>(H3, gc2_w, H4, 512, 512, 512, 128, gc2_b);
        bnstats_v10<<<2,256,0,stream>>>(H4, bn2_g, bn2_b, BN2S, BN2H, 128);
        feat_v10  <<<2,128,0,stream>>>(H4, BN2S, BN2H, FEAT);
    }
    cls_v10   <<<1,64,0,stream>>>(FEAT, cls_w, cls_b, out);
}

// Round 8
// 372.712 us; speedup vs baseline: 1.5704x; 1.5704x over previous
//
#include <hip/hip_runtime.h>
#include <hip/hip_bf16.h>

// B=2, N=512, FDIM=1024, HEADS=4, DH=256, AH=256, HID=512, OUT=128, NCLS=10
// NN=262144, rank = 52429. Inputs fp32, output fp32[20].

// ================= 64x64 fp32 GEMM (8x8/lane, wave-private k-slices) =================
// ksplit>1: z%ksplit = K-chunk -> PARTIAL buffer at C + kz*pstride (normal stores);
//           z/ksplit selects (Bm2,C2,bias2). Partials summed by foldk afterwards.
__global__ __launch_bounds__(256) void gemm64_nt(
    const float* __restrict__ A, const float* __restrict__ Bm, float* __restrict__ C,
    int K, int lda, int ldb, int ldc, const float* __restrict__ bias,
    const float* __restrict__ Bm2, float* __restrict__ C2, const float* __restrict__ bias2,
    int ksplit, long pstride)
{
    if (ksplit > 1){
        int z = blockIdx.z;
        int kz = z % ksplit;
        if (z / ksplit){ Bm = Bm2; C = C2; bias = bias2; }
        A += (size_t)kz * K; Bm += (size_t)kz * K;
        C += (long)kz * pstride;
        if (kz) bias = nullptr;
    } else if (blockIdx.z){
        Bm = Bm2; C = C2; bias = bias2;
    }
    __shared__ float As[64][64], Bs[64][64];
    int t = threadIdx.x;
    int m0 = blockIdx.y*64, n0 = blockIdx.x*64;
    int w = t>>6, lane = t&63;
    int mi = lane>>3, ni = lane&7;
    int kc = w*16;                            // wave's private k-slice in the tile
    const float* Ar = A + (size_t)(m0+lane)*lda + kc;
    const float* Br = Bm + (size_t)(n0+lane)*ldb + kc;
    float4 pa[4], pb[4];
    #pragma unroll
    for (int j=0;j<4;++j){ pa[j]=*(const float4*)(Ar+j*4); pb[j]=*(const float4*)(Br+j*4); }
    float acc[8][8] = {};
    for (int k0=0; k0<K; k0+=64){
        #pragma unroll
        for (int j=0;j<4;++j){
            As[kc+j*4+0][lane]=pa[j].x; As[kc+j*4+1][lane]=pa[j].y;
            As[kc+j*4+2][lane]=pa[j].z; As[kc+j*4+3][lane]=pa[j].w;
            Bs[kc+j*4+0][lane]=pb[j].x; Bs[kc+j*4+1][lane]=pb[j].y;
            Bs[kc+j*4+2][lane]=pb[j].z; Bs[kc+j*4+3][lane]=pb[j].w;
        }
        if (k0+64 < K){
            #pragma unroll
            for (int j=0;j<4;++j){
                pa[j]=*(const float4*)(Ar+k0+64+j*4);
                pb[j]=*(const float4*)(Br+k0+64+j*4);
            }
        }
        #pragma unroll
        for (int kk=0; kk<16; ++kk){
            float4 a0=*(const float4*)&As[kc+kk][mi*8], a1=*(const float4*)&As[kc+kk][mi*8+4];
            float4 b0=*(const float4*)&Bs[kc+kk][ni*8], b1=*(const float4*)&Bs[kc+kk][ni*8+4];
            float am[8]={a0.x,a0.y,a0.z,a0.w,a1.x,a1.y,a1.z,a1.w};
            float bn[8]={b0.x,b0.y,b0.z,b0.w,b1.x,b1.y,b1.z,b1.w};
            #pragma unroll
            for (int i=0;i<8;++i)
                #pragma unroll
                for (int j2=0;j2<8;++j2) acc[i][j2] += am[i]*bn[j2];
        }
    }
    // ---- reduce 4 wave k-partials through LDS (reuse As/Bs as scratch) ----
    __syncthreads();
    float* s0 = &As[0][0]; float* s1 = &Bs[0][0];
    if (w>=2){
        float* d = (w==2)? s0 : s1;
        #pragma unroll
        for (int i=0;i<8;++i){
            *(float4*)&d[(mi*8+i)*64+ni*8]   = make_float4(acc[i][0],acc[i][1],acc[i][2],acc[i][3]);
            *(float4*)&d[(mi*8+i)*64+ni*8+4] = make_float4(acc[i][4],acc[i][5],acc[i][6],acc[i][7]);
        }
    }
    __syncthreads();
    if (w<2){
        const float* sv = (w==0)? s0 : s1;
        #pragma unroll
        for (int i=0;i<8;++i){
            float4 v0=*(const float4*)&sv[(mi*8+i)*64+ni*8];
            float4 v1=*(const float4*)&sv[(mi*8+i)*64+ni*8+4];
            acc[i][0]+=v0.x; acc[i][1]+=v0.y; acc[i][2]+=v0.z; acc[i][3]+=v0.w;
            acc[i][4]+=v1.x; acc[i][5]+=v1.y; acc[i][6]+=v1.z; acc[i][7]+=v1.w;
        }
    }
    __syncthreads();
    if (w==1){
        #pragma unroll
        for (int i=0;i<8;++i){
            *(float4*)&s0[(mi*8+i)*64+ni*8]   = make_float4(acc[i][0],acc[i][1],acc[i][2],acc[i][3]);
            *(float4*)&s0[(mi*8+i)*64+ni*8+4] = make_float4(acc[i][4],acc[i][5],acc[i][6],acc[i][7]);
        }
    }
    __syncthreads();
    if (w==0){
        #pragma unroll
        for (int i=0;i<8;++i){
            float4 v0=*(const float4*)&s0[(mi*8+i)*64+ni*8];
            float4 v1=*(const float4*)&s0[(mi*8+i)*64+ni*8+4];
            acc[i][0]+=v0.x; acc[i][1]+=v0.y; acc[i][2]+=v0.z; acc[i][3]+=v0.w;
            acc[i][4]+=v1.x; acc[i][5]+=v1.y; acc[i][6]+=v1.z; acc[i][7]+=v1.w;
        }
        float bb[8];
        #pragma unroll
        for (int j2=0;j2<8;++j2) bb[j2] = bias ? bias[n0+ni*8+j2] : 0.f;
        #pragma unroll
        for (int i=0;i<8;++i){
            *(float4*)&C[(size_t)(m0+mi*8+i)*ldc + n0+ni*8]   =
                make_float4(acc[i][0]+bb[0],acc[i][1]+bb[1],acc[i][2]+bb[2],acc[i][3]+bb[3]);
            *(float4*)&C[(size_t)(m0+mi*8+i)*ldc + n0+ni*8+4] =
                make_float4(acc[i][4]+bb[4],acc[i][5]+bb[5],acc[i][6]+bb[6],acc[i][7]+bb[7]);
        }
    }
}

// NN batched: C[m][n] = sum_k A[m][k]*B[k][n], optional bn-relu fused on B columns.
// bhmode: z -> b=z>>2,h=z&3; B/C offset = b*sB + h*256 (attention PV addressing).
// ksplit>1 (non-bhmode): z = bz*ksplit + kz; partial at C + bz*sC + kz*pstride.
__global__ __launch_bounds__(256) void gemm64_nn(
    const float* __restrict__ A, const float* __restrict__ Bm, float* __restrict__ C,
    int K, int lda, int ldb, int ldc, long sA, long sB, long sC,
    const float* __restrict__ bsc, const float* __restrict__ bsh, int bhmode,
    int ksplit, long pstride)
{
    if (bhmode){
        int z = blockIdx.z;
        A  += (size_t)z*sA;
        Bm += (size_t)(z>>2)*sB + (size_t)(z&3)*256;
        C  += (size_t)(z>>2)*sC + (size_t)(z&3)*256;
    } else {
        int z = blockIdx.z;
        int bz = z, kz = 0;
        if (ksplit > 1){ bz = z / ksplit; kz = z % ksplit; }
        A  += (long)bz*sA + (size_t)kz*K;
        Bm += (long)bz*sB + (size_t)kz*K*ldb;
        C  += (long)bz*sC + (long)kz*pstride;
    }
    __shared__ float As[64][64], Bs[64][64];
    int t=threadIdx.x, w=t>>6, lane=t&63;
    int m0=blockIdx.y*64, n0=blockIdx.x*64;
    int mi=lane>>3, ni=lane&7;
    int kc=w*16;
    const float* Ar = A + (size_t)(m0+lane)*lda + kc;
    int kr = lane>>4, nc = (lane&15)*4;
    const float* Br = Bm + (size_t)(kc+kr)*ldb + n0 + nc;
    float4 sc4 = make_float4(1,1,1,1), sh4 = make_float4(0,0,0,0);
    if (bsc){ sc4 = *(const float4*)&bsc[n0+nc]; sh4 = *(const float4*)&bsh[n0+nc]; }
    float4 pa[4], pb[4];
    #pragma unroll
    for (int j=0;j<4;++j){
        pa[j]=*(const float4*)(Ar+j*4);
        pb[j]=*(const float4*)(Br + (size_t)(j*4)*ldb);
    }
    float acc[8][8] = {};
    for (int k0=0; k0<K; k0+=64){
        #pragma unroll
        for (int j=0;j<4;++j){
            As[kc+j*4+0][lane]=pa[j].x; As[kc+j*4+1][lane]=pa[j].y;
            As[kc+j*4+2][lane]=pa[j].z; As[kc+j*4+3][lane]=pa[j].w;
            float4 bv = pb[j];
            if (bsc){
                bv.x=fmaxf(bv.x*sc4.x+sh4.x,0.f); bv.y=fmaxf(bv.y*sc4.y+sh4.y,0.f);
                bv.z=fmaxf(bv.z*sc4.z+sh4.z,0.f); bv.w=fmaxf(bv.w*sc4.w+sh4.w,0.f);
            }
            *(float4*)&Bs[kc+kr+j*4][nc] = bv;
        }
        if (k0+64 < K){
            #pragma unroll
            for (int j=0;j<4;++j){
                pa[j]=*(const float4*)(Ar+k0+64+j*4);
                pb[j]=*(const float4*)(Br + (size_t)(k0+64+j*4)*ldb);
            }
        }
        #pragma unroll
        for (int kk=0; kk<16; ++kk){
            float4 a0=*(const float4*)&As[kc+kk][mi*8], a1=*(const float4*)&As[kc+kk][mi*8+4];
            float4 b0=*(const float4*)&Bs[kc+kk][ni*8], b1=*(const float4*)&Bs[kc+kk][ni*8+4];
            float am[8]={a0.x,a0.y,a0.z,a0.w,a1.x,a1.y,a1.z,a1.w};
            float bn[8]={b0.x,b0.y,b0.z,b0.w,b1.x,b1.y,b1.z,b1.w};
            #pragma unroll
            for (int i=0;i<8;++i)
                #pragma unroll
                for (int j2=0;j2<8;++j2) acc[i][j2] += am[i]*bn[j2];
        }
    }
    __syncthreads();
    float* s0 = &As[0][0]; float* s1 = &Bs[0][0];
    if (w>=2){
        float* d = (w==2)? s0 : s1;
        #pragma unroll
        for (int i=0;i<8;++i){
            *(float4*)&d[(mi*8+i)*64+ni*8]   = make_float4(acc[i][0],acc[i][1],acc[i][2],acc[i][3]);
            *(float4*)&d[(mi*8+i)*64+ni*8+4] = make_float4(acc[i][4],acc[i][5],acc[i][6],acc[i][7]);
        }
    }
    __syncthreads();
    if (w<2){
        const float* sv = (w==0)? s0 : s1;
        #pragma unroll
        for (int i=0;i<8;++i){
            float4 v0=*(const float4*)&sv[(mi*8+i)*64+ni*8];
            float4 v1=*(const float4*)&sv[(mi*8+i)*64+ni*8+4];
            acc[i][0]+=v0.x; acc[i][1]+=v0.y; acc[i][2]+=v0.z; acc[i][3]+=v0.w;
            acc[i][4]+=v1.x; acc[i][5]+=v1.y; acc[i][6]+=v1.z; acc[i][7]+=v1.w;
        }
    }
    __syncthreads();
    if (w==1){
        #pragma unroll
        for (int i=0;i<8;++i){
            *(float4*)&s0[(mi*8+i)*64+ni*8]   = make_float4(acc[i][0],acc[i][1],acc[i][2],acc[i][3]);
            *(float4*)&s0[(mi*8+i)*64+ni*8+4] = make_float4(acc[i][4],acc[i][5],acc[i][6],acc[i][7]);
        }
    }
    __syncthreads();
    if (w==0){
        #pragma unroll
        for (int i=0;i<8;++i){
            float4 v0=*(const float4*)&s0[(mi*8+i)*64+ni*8];
            float4 v1=*(const float4*)&s0[(mi*8+i)*64+ni*8+4];
            acc[i][0]+=v0.x; acc[i][1]+=v0.y; acc[i][2]+=v0.z; acc[i][3]+=v0.w;
            acc[i][4]+=v1.x; acc[i][5]+=v1.y; acc[i][6]+=v1.z; acc[i][7]+=v1.w;
        }
        #pragma unroll
        for (int i=0;i<8;++i){
            *(float4*)&C[(size_t)(m0+mi*8+i)*ldc + n0+ni*8]   =
                make_float4(acc[i][0],acc[i][1],acc[i][2],acc[i][3]);
            *(float4*)&C[(size_t)(m0+mi*8+i)*ldc + n0+ni*8+4] =
                make_float4(acc[i][4],acc[i][5],acc[i][6],acc[i][7]);
        }
    }
}

// ---------------- fold k partials: dst[i] = sum_{p<k} src[p*pstride + i] ----------------
__global__ void foldk(float* __restrict__ dst, const float* __restrict__ src,
                      long pstride, int kparts, int n4){
    int i = blockIdx.x*256 + threadIdx.x;
    if (i < n4){
        float4 s = *(const float4*)&src[(size_t)i*4];
        for (int p=1;p<kparts;++p){
            float4 v = *(const float4*)&src[(long)p*pstride + (size_t)i*4];
            s.x+=v.x; s.y+=v.y; s.z+=v.z; s.w+=v.w;
        }
        *(float4*)&dst[(size_t)i*4] = s;
    }
}

// ---------------- PJ (1024x256) -> pjT[b][a][n] transpose via LDS ----------------
__global__ void transp_v15(const float* __restrict__ PJ, float* __restrict__ pjT){
    __shared__ float T[64][68];
    int b = blockIdx.z;
    int a0 = blockIdx.x*64, n0 = blockIdx.y*64;
    int t = threadIdx.x;
    int c = t&15, r = t>>4;
    for (int rr=r; rr<64; rr+=16){
        float4 v = *(const float4*)&PJ[(size_t)(b*512+n0+rr)*256 + a0 + c*4];
        T[rr][c*4]=v.x; T[rr][c*4+1]=v.y; T[rr][c*4+2]=v.z; T[rr][c*4+3]=v.w;
    }
    __syncthreads();
    for (int rr=r; rr<64; rr+=16){
        float4 o = make_float4(T[c*4][rr], T[c*4+1][rr], T[c*4+2][rr], T[c*4+3][rr]);
        *(float4*)&pjT[(size_t)b*131072 + (size_t)(a0+rr)*512 + n0 + c*4] = o;
    }
}

// ---------------- parallel batchnorm stats: stage1 (64 rows x 64 feats per block) ------
__global__ void bnp1(const float* __restrict__ src, float* __restrict__ PS,
                     float* __restrict__ PS2, int F){
    int f0 = blockIdx.x*64, r0 = blockIdx.y*64;
    int fi = threadIdx.x & 63, rg = threadIdx.x >> 6;
    float s=0.f, s2=0.f;
    #pragma unroll
    for (int i=0;i<16;++i){
        float v = src[(size_t)(r0+rg+i*4)*F + f0+fi];
        s += v; s2 += v*v;
    }
    __shared__ float ls[4][64], ls2[4][64];
    ls[rg][fi]=s; ls2[rg][fi]=s2; __syncthreads();
    if (rg==0){
        PS [blockIdx.y*F + f0+fi] = ls[0][fi]+ls[1][fi]+ls[2][fi]+ls[3][fi];
        PS2[blockIdx.y*F + f0+fi] = ls2[0][fi]+ls2[1][fi]+ls2[2][fi]+ls2[3][fi];
    }
}

// ---------------- stage2: fold 16 chunks, produce scale/shift ----------------
__global__ void bnp2(const float* __restrict__ PS, const float* __restrict__ PS2,
                     const float* __restrict__ g, const float* __restrict__ be,
                     float* __restrict__ scale, float* __restrict__ shift, int F){
    int f = blockIdx.x*64 + threadIdx.x;
    float S=0.f, S2=0.f;
    #pragma unroll
    for (int c=0;c<16;++c){ S += PS[c*F+f]; S2 += PS2[c*F+f]; }
    float m  = S*(1.f/1024.f);
    float var = S2*(1.f/1024.f) - m*m;
    float sc = g[f] * rsqrtf(var + 1e-5f);
    scale[f]=sc; shift[f]=be[f] - m*sc;
}

// ---------------- parallel bn2+relu+mean: stage1 (64 rows per block) ----------------
__global__ void feat_p(const float* __restrict__ h4, const float* __restrict__ sc,
                       const float* __restrict__ sh, float* __restrict__ featp){
    int b = blockIdx.x, chunk = blockIdx.y;
    int t = threadIdx.x;              // 128
    float s = sc[t], o = sh[t], acc = 0.f;
    int n0 = chunk*64;
    #pragma unroll
    for (int i=0;i<64;++i){
        float v = h4[(size_t)(b*512+n0+i)*128 + t]*s + o;
        acc += fmaxf(v, 0.f);
    }
    featp[(b*8+chunk)*128 + t] = acc;
}

__global__ void feat_f(const float* __restrict__ featp, float* __restrict__ feat){
    int b = blockIdx.x, t = threadIdx.x;
    float a = 0.f;
    #pragma unroll
    for (int c=0;c<8;++c) a += featp[(b*8+c)*128 + t];
    feat[b*128+t] = a*(1.f/512.f);
}

// ================= legacy kernels (fallback non-ws path) =================
__global__ void gemm_nn32(const float* __restrict__ A, const float* __restrict__ Bm,
                          float* __restrict__ C, int K, int lda, int ldb, int ldc,
                          long sA, long sB, long sC,
                          const float* __restrict__ bsc, const float* __restrict__ bsh){
    A  += (long)blockIdx.z * sA;
    Bm += (long)blockIdx.z * sB;
    C  += (long)blockIdx.z * sC;
    __shared__ float As[16][32], Bs[16][64];
    int n0 = blockIdx.x*64, m0 = blockIdx.y*32;
    int t = threadIdx.x, tx = t & 15, ty = t >> 4;
    int sr = t >> 3, sk = (t & 7)*2;
    int bk = t >> 4, bn4 = (t & 15)*4;
    float acc[2][4] = {};
    for (int k0=0; k0<K; k0+=16){
        #pragma unroll
        for (int i=0;i<2;++i) As[sk+i][sr] = A[(size_t)(m0+sr)*lda + k0+sk+i];
        float4 bv = *(const float4*)&Bm[(size_t)(k0+bk)*ldb + n0+bn4];
        if (bsc){
            bv.x = fmaxf(bv.x*bsc[n0+bn4+0]+bsh[n0+bn4+0], 0.f);
            bv.y = fmaxf(bv.y*bsc[n0+bn4+1]+bsh[n0+bn4+1], 0.f);
            bv.z = fmaxf(bv.z*bsc[n0+bn4+2]+bsh[n0+bn4+2], 0.f);
            bv.w = fmaxf(bv.w*bsc[n0+bn4+3]+bsh[n0+bn4+3], 0.f);
        }
        *(float4*)&Bs[bk][bn4] = bv;
        __syncthreads();
        #pragma unroll
        for (int k=0;k<16;++k){
            float a0 = As[k][ty*2], a1 = As[k][ty*2+1];
            float4 b = *(const float4*)&Bs[k][tx*4];
            acc[0][0]+=a0*b.x; acc[0][1]+=a0*b.y; acc[0][2]+=a0*b.z; acc[0][3]+=a0*b.w;
            acc[1][0]+=a1*b.x; acc[1][1]+=a1*b.y; acc[1][2]+=a1*b.z; acc[1][3]+=a1*b.w;
        }
        __syncthreads();
    }
    #pragma unroll
    for (int i=0;i<2;++i){
        float4 v = make_float4(acc[i][0],acc[i][1],acc[i][2],acc[i][3]);
        *(float4*)&C[(size_t)(m0+ty*2+i)*ldc + n0+tx*4] = v;
    }
}

__global__ void gemm_nt32(const float* __restrict__ A, const float* __restrict__ Bm,
                          float* __restrict__ C, int K, int lda, int ldb, int ldc,
                          const float* __restrict__ bias){
    __shared__ float As[16][32], Bs[16][64];
    int n0 = blockIdx.x*64, m0 = blockIdx.y*32;
    int t = threadIdx.x, tx = t & 15, ty = t >> 4;
    int sr = t >> 3, sk = (t & 7)*2;
    int bn = t >> 2, bkk = (t & 3)*4;         // B^T staging: row bn, 4 k's
    float acc[2][4] = {};
    for (int k0=0; k0<K; k0+=16){
        #pragma unroll
        for (int i=0;i<2;++i) As[sk+i][sr] = A[(size_t)(m0+sr)*lda + k0+sk+i];
        float4 wv = *(const float4*)&Bm[(size_t)(n0+bn)*ldb + k0+bkk];
        Bs[bkk+0][bn]=wv.x; Bs[bkk+1][bn]=wv.y; Bs[bkk+2][bn]=wv.z; Bs[bkk+3][bn]=wv.w;
        __syncthreads();
        #pragma unroll
        for (int k=0;k<16;++k){
            float a0 = As[k][ty*2], a1 = As[k][ty*2+1];
            float4 b = *(const float4*)&Bs[k][tx*4];
            acc[0][0]+=a0*b.x; acc[0][1]+=a0*b.y; acc[0][2]+=a0*b.z; acc[0][3]+=a0*b.w;
            acc[1][0]+=a1*b.x; acc[1][1]+=a1*b.y; acc[1][2]+=a1*b.z; acc[1][3]+=a1*b.w;
        }
        __syncthreads();
    }
    float4 bb = bias ? *(const float4*)&bias[n0+tx*4] : make_float4(0,0,0,0);
    #pragma unroll
    for (int i=0;i<2;++i){
        float4 v = make_float4(acc[i][0]+bb.x,acc[i][1]+bb.y,acc[i][2]+bb.z,acc[i][3]+bb.w);
        *(float4*)&C[(size_t)(m0+ty*2+i)*ldc + n0+tx*4] = v;
    }
}

__global__ void gemm_x_v12(const float* __restrict__ X, const float* __restrict__ Wg,
                           float* __restrict__ dst){
    __shared__ float xs[4][1024];
    int m0 = blockIdx.x*4;
    int t = threadIdx.x;
    for (int i=t;i<4096;i+=256){ int r=i>>10, c=i&1023; xs[r][c]=X[(size_t)(m0+r)*1024+c]; }
    __syncthreads();
    const float* w0 = Wg + (size_t)(t*4)*1024;
    float acc[4][4] = {};
    for (int k0=0;k0<1024;k0+=16){
        float4 xv[4][4];
        #pragma unroll
        for (int r=0;r<4;++r)
            #pragma unroll
            for (int c=0;c<4;++c) xv[r][c] = *(const float4*)&xs[r][k0+4*c];
        #pragma unroll
        for (int j=0;j<4;++j){
            const float* wr = w0 + (size_t)j*1024 + k0;
            #pragma unroll
            for (int c=0;c<4;++c){
                float4 w = *(const float4*)(wr + 4*c);
                #pragma unroll
                for (int r=0;r<4;++r)
                    acc[r][j] += xv[r][c].x*w.x + xv[r][c].y*w.y
                               + xv[r][c].z*w.z + xv[r][c].w*w.w;
            }
        }
    }
    int n0 = t*4;
    #pragma unroll
    for (int r=0;r<4;++r){
        float4 v = make_float4(acc[r][0],acc[r][1],acc[r][2],acc[r][3]);
        *(float4*)&dst[(size_t)(m0+r)*1024 + n0] = v;
    }
}

__global__ void attn_v12(const float* __restrict__ hp, const float* __restrict__ attn,
                         float* __restrict__ nf){
    int blk = blockIdx.x;
    int bh = blk >> 6, i0 = (blk & 63)*8;
    int b = bh >> 2, h = bh & 3;
    int t = threadIdx.x;
    __shared__ float ais[256], ajs[256], sjs[512], sis[8], inv[8];
    __shared__ float alpha[8][512];
    __shared__ float red[256];
    ais[t] = attn[h*512 + t];
    ajs[t] = attn[h*512 + 256 + t];
    __syncthreads();
    const float* hpb = hp + (size_t)b*524288 + h*256;
    for (int j=t; j<512; j+=256){
        const float* row = hpb + (size_t)j*1024;
        float s=0.f;
        for (int d=0; d<256; ++d) s += row[d]*ajs[d];
        sjs[j]=s;
    }
    if (t<8){
        const float* row = hpb + (size_t)(i0+t)*1024;
        float s=0.f;
        for (int d=0; d<256; ++d) s += row[d]*ais[d];
        sis[t]=s;
    }
    __syncthreads();
    for (int ii=0; ii<8; ++ii){
        float si = sis[ii];
        float e0 = si + sjs[t], e1 = si + sjs[t+256];
        e0 = (e0>=0.f)? e0 : 0.2f*e0;
        e1 = (e1>=0.f)? e1 : 0.2f*e1;
        float p0 = expf(e0), p1 = expf(e1);
        alpha[ii][t]=p0; alpha[ii][t+256]=p1;
        red[t]=p0+p1; __syncthreads();
        for (int s=128; s>0; s>>=1){ if (t<s) red[t]+=red[t+s]; __syncthreads(); }
        if (t==0) inv[ii] = 1.0f/red[0];
        __syncthreads();
    }
    float acc[8] = {};
    for (int j=0; j<512; ++j){
        float r = hpb[(size_t)j*1024 + t];
        #pragma unroll
        for (int ii=0; ii<8; ++ii) acc[ii] += alpha[ii][j]*r;
    }
    #pragma unroll
    for (int ii=0; ii<8; ++ii)
        nf[(size_t)(b*512+i0+ii)*1024 + h*256 + t] = acc[ii]*inv[ii];
}

// ---------------- s_i / s_j precompute ----------------
__global__ void sij_v14(const float* __restrict__ hp, const float* __restrict__ attn,
                        float* __restrict__ SI, float* __restrict__ SJ){
    int t = threadIdx.x;
    int lane = t & 63, w = t >> 6;
    int h  = lane >> 4;
    int e0 = (lane & 15) * 16;
    const float* ai = attn + h*512 + e0;
    const float* aj = ai + 256;
    float4 wi[4], wj[4];
    #pragma unroll
    for (int q=0;q<4;++q){ wi[q] = *(const float4*)(ai + 4*q); wj[q] = *(const float4*)(aj + 4*q); }
    int row0 = blockIdx.x*16 + w*4;
    for (int r=0;r<4;++r){
        int row = row0 + r;
        const float* hr = hp + (size_t)row*1024 + h*256 + e0;
        float si=0.f, sj=0.f;
        #pragma unroll
        for (int q=0;q<4;++q){
            float4 v = *(const float4*)(hr + 4*q);
            si += v.x*wi[q].x + v.y*wi[q].y + v.z*wi[q].z + v.w*wi[q].w;
            sj += v.x*wj[q].x + v.y*wj[q].y + v.z*wj[q].z + v.w*wj[q].w;
        }
        #pragma unroll
        for (int s=1;s<16;s<<=1){
            si += __shfl_xor(si, s, 64);
            sj += __shfl_xor(sj, s, 64);
        }
        if ((lane & 15)==0){
            int b = row >> 9, n = row & 511;
            SI[(size_t)(b*4+h)*512 + n] = si;
            SJ[(size_t)(b*4+h)*512 + n] = sj;
        }
    }
}

// ---------------- alpha materialization: exp(leaky(si+sj))*inv -> ALP[bh][i][j] --------
__global__ __launch_bounds__(512) void asm_v17(const float* __restrict__ SI,
                                               const float* __restrict__ SJ,
                                               float* __restrict__ ALP){
    int blk = blockIdx.x;                 // 256 blocks
    int bh = blk >> 5, i0 = (blk & 31)*16;
    int t = threadIdx.x;                  // 512 = all j
    int w = t >> 6, lane = t & 63;
    __shared__ float wsum[8][16];
    __shared__ float inv[16];
    float sj = SJ[(size_t)bh*512 + t];
    const float* sip = SI + (size_t)bh*512 + i0;
    float p[16], part[16];
    #pragma unroll
    for (int ii=0; ii<16; ++ii){
        float e = sip[ii] + sj;
        e = (e>=0.f)? e : 0.2f*e;
        p[ii] = expf(e);
        part[ii] = p[ii];
    }
    #pragma unroll
    for (int s=1;s<64;s<<=1){
        #pragma unroll
        for (int ii=0;ii<16;++ii) part[ii] += __shfl_xor(part[ii], s, 64);
    }
    if (lane==0){
        #pragma unroll
        for (int ii=0;ii<16;++ii) wsum[w][ii] = part[ii];
    }
    __syncthreads();
    if (t<16){
        float s=0.f;
        #pragma unroll
        for (int ww=0;ww<8;++ww) s += wsum[ww][t];
        inv[t] = 1.0f/s;
    }
    __syncthreads();
    float* dst = ALP + (size_t)bh*262144 + (size_t)i0*512 + t;
    #pragma unroll
    for (int ii=0; ii<16; ++ii)
        dst[(size_t)ii*512] = p[ii]*inv[ii];
}

// ---------------- legacy pipj (fallback path) ----------------
__global__ void pipj_v13(const float* __restrict__ nf, const float* __restrict__ W1,
                         const float* __restrict__ b1, float* __restrict__ pi,
                         float* __restrict__ pjT){
    int half = blockIdx.z >> 5;
    int m0 = (blockIdx.z & 31)*32;
    int a0 = blockIdx.x*64;
    __shared__ float As[16][32], Bs[16][64];
    int t = threadIdx.x, tx = t & 15, ty = t >> 4;
    int sr = t >> 3, sk = (t & 7)*2;
    int bn = t >> 2, bkk = (t & 3)*4;
    const float* Wbase = W1 + (half ? 1024 : 0);
    float acc[2][4] = {};
    for (int k0=0; k0<1024; k0+=16){
        #pragma unroll
        for (int i=0;i<2;++i) As[sk+i][sr] = nf[(size_t)(m0+sr)*1024 + k0+sk+i];
        float4 wv = *(const float4*)&Wbase[(size_t)(a0+bn)*2048 + k0+bkk];
        Bs[bkk+0][bn]=wv.x; Bs[bkk+1][bn]=wv.y; Bs[bkk+2][bn]=wv.z; Bs[bkk+3][bn]=wv.w;
        __syncthreads();
        #pragma unroll
        for (int k=0;k<16;++k){
            float a0v = As[k][ty*2], a1v = As[k][ty*2+1];
            float4 b = *(const float4*)&Bs[k][tx*4];
            acc[0][0]+=a0v*b.x; acc[0][1]+=a0v*b.y; acc[0][2]+=a0v*b.z; acc[0][3]+=a0v*b.w;
            acc[1][0]+=a1v*b.x; acc[1][1]+=a1v*b.y; acc[1][2]+=a1v*b.z; acc[1][3]+=a1v*b.w;
        }
        __syncthreads();
    }
    if (!half){
        float4 bb = *(const float4*)&b1[a0+tx*4];
        #pragma unroll
        for (int i=0;i<2;++i){
            float4 v = make_float4(acc[i][0]+bb.x,acc[i][1]+bb.y,acc[i][2]+bb.z,acc[i][3]+bb.w);
            *(float4*)&pi[(size_t)(m0+ty*2+i)*256 + a0+tx*4] = v;
        }
    } else {
        #pragma unroll
        for (int i=0;i<2;++i){
            int m = m0+ty*2+i;
            size_t base = (size_t)(m>>9)*131072 + (m&511);
            #pragma unroll
            for (int j=0;j<4;++j)
                pjT[base + (size_t)(a0+tx*4+j)*512] = acc[i][j];
        }
    }
}

// ---------------- edge scores ----------------
__global__ void edge_v10(const float* __restrict__ pi, const float* __restrict__ pjT,
                         const float* __restrict__ w2, const float* __restrict__ b2,
                         float* __restrict__ es){
    int blk = blockIdx.x;
    int b = blk >> 8, i0 = (blk & 255)*2;
    int t = threadIdx.x;
    __shared__ float pis[2][256], w2s[256];
    w2s[t] = w2[t];
    pis[0][t] = pi[(size_t)(b*512+i0)*256 + t];
    pis[1][t] = pi[(size_t)(b*512+i0+1)*256 + t];
    __syncthreads();
    float a00=0,a01=0,a10=0,a11=0;
    const float* pj = pjT + (size_t)b*131072;
    for (int a=0; a<256; ++a){
        float pv0 = pj[(size_t)a*512 + t];
        float pv1 = pj[(size_t)a*512 + t + 256];
        float w  = w2s[a];
        a00 += fmaxf(pis[0][a]+pv0, 0.f)*w;
        a01 += fmaxf(pis[0][a]+pv1, 0.f)*w;
        a10 += fmaxf(pis[1][a]+pv0, 0.f)*w;
        a11 += fmaxf(pis[1][a]+pv1, 0.f)*w;
    }
    float b2f = b2[0];
    es[(size_t)(b*512+i0+0)*512 + t]       = a00 + b2f;
    es[(size_t)(b*512+i0+0)*512 + t + 256] = a01 + b2f;
    es[(size_t)(b*512+i0+1)*512 + t]       = a10 + b2f;
    es[(size_t)(b*512+i0+1)*512 + t + 256] = a11 + b2f;
}

// ---------------- exp(2*es) in place + sum ----------------
__global__ void k_exp_v13(float* __restrict__ u, float* __restrict__ S){
    int b = blockIdx.x >> 8;
    size_t base = (size_t)b*262144 + (size_t)(blockIdx.x & 255)*1024;
    int t = threadIdx.x;
    float acc = 0.f;
    for (int i=t;i<1024;i+=256){ float v = expf(u[base+i]*2.0f); u[base+i]=v; acc+=v; }
    __shared__ float red[256];
    red[t]=acc; __syncthreads();
    for (int s=128;s>0;s>>=1){ if(t<s) red[t]+=red[t+s]; __syncthreads(); }
    if (t==0) atomicAdd(&S[b], red[0]);
}

// ---------------- parallel radix histogram ----------------
__global__ void k_hist_v11(const float* __restrict__ u, unsigned* __restrict__ hist,
                           const unsigned* __restrict__ pfx, int cmpShift, int shift,
                           unsigned mask, int nbins){
    __shared__ unsigned h[2048];
    for (int i=threadIdx.x;i<nbins;i+=256) h[i]=0;
    __syncthreads();
    int b = blockIdx.x>>6;
    size_t base = (size_t)b*262144 + (size_t)(blockIdx.x&63)*4096;
    unsigned p = pfx ? pfx[b] : 0u;
    for (int i=threadIdx.x;i<4096;i+=256){
        unsigned bits = __float_as_uint(u[base+i]);
        if (!pfx || (bits>>cmpShift)==p) atomicAdd(&h[(bits>>shift)&mask],1u);
    }
    __syncthreads();
    for (int i=threadIdx.x;i<nbins;i+=256) if (h[i]) atomicAdd(&hist[b*nbins+i], h[i]);
}

// ---------------- scan histogram, descend one level ----------------
__global__ void k_scan_v11(const unsigned* __restrict__ hist, int nbins,
                           unsigned* __restrict__ pfx, unsigned* __restrict__ rank,
                           int passBits, int first, float* __restrict__ thrOut){
    __shared__ unsigned part[2][256];
    int batch = threadIdx.x>>8, lane = threadIdx.x&255;
    int chunk = nbins/256;
    const unsigned* hb = hist + batch*nbins;
    unsigned s=0;
    for (int i=0;i<chunk;++i) s += hb[lane*chunk+i];
    part[batch][lane]=s;
    __syncthreads();
    if (lane==0){
        unsigned r = first ? 52429u : rank[batch];
        unsigned cum=0; int c=0;
        for (;c<256;++c){ unsigned pc=part[batch][c]; if (cum+pc>r) break; cum+=pc; }
        if (c==256) c=255;
        int bin=c*chunk;
        for (int i=0;i<chunk;++i){ unsigned cnt=hb[c*chunk+i]; if (cum+cnt>r){ bin=c*chunk+i; break;} cum+=cnt; }
        rank[batch]=r-cum;
        unsigned np = ((first?0u:pfx[batch])<<passBits) | (unsigned)bin;
        pfx[batch]=np;
        if (thrOut) thrOut[batch]=__uint_as_float(np);
    }
}

// ---------------- parallel kept-sum/count ----------------
__global__ void k_csum_v11(const float* __restrict__ u, const float* __restrict__ THR,
                           float* __restrict__ CS, unsigned* __restrict__ KC){
    int b = blockIdx.x>>6;
    size_t base = (size_t)b*262144 + (size_t)(blockIdx.x&63)*4096;
    float th = THR[b];
    float cs=0.f; unsigned kc=0;
    for (int i=threadIdx.x;i<4096;i+=256){ float v=u[base+i]; if (v>=th){ cs+=v; kc++; } }
    __shared__ float rf[256]; __shared__ unsigned ru[256];
    rf[threadIdx.x]=cs; ru[threadIdx.x]=kc; __syncthreads();
    for (int s=128;s>0;s>>=1){ if(threadIdx.x<s){ rf[threadIdx.x]+=rf[threadIdx.x+s]; ru[threadIdx.x]+=ru[threadIdx.x+s]; } __syncthreads(); }
    if (threadIdx.x==0){ atomicAdd(&CS[b], rf[0]); atomicAdd(&KC[b], ru[0]); }
}

// ---------------- finalize thr/dinv ----------------
__global__ void k_fin_v11(const float* __restrict__ S, const float* __restrict__ CS,
                          const unsigned* __restrict__ KC, float* __restrict__ THR,
                          float* __restrict__ DINV){
    int t = threadIdx.x;
    if (t < 2){
        float ks = CS[t]; float th = THR[t];
        if (KC[t] < 209715u){ th = 0.f; ks = S[t]; }
        THR[t]=th;
        DINV[t]=1.0f/(ks + 1e-12f*S[t]);
    }
}

// ---------------- adjacency, in place over u ----------------
__global__ void adj_v10(float* __restrict__ u, const float* __restrict__ thrU,
                        const float* __restrict__ dinv){
    int idx = blockIdx.x*256 + threadIdx.x;
    int b = idx >> 18;
    float v = u[idx];
    u[idx] = (v >= thrU[b]) ? v*dinv[b] : 0.0f;
}

// ---------------- legacy batchnorm stats (fallback path) ----------------
__global__ void bnstats_v10(const float* __restrict__ src, const float* __restrict__ g,
                            const float* __restrict__ be, float* __restrict__ scale,
                            float* __restrict__ shift, int F){
    int f0 = blockIdx.x*64;
    int fi = threadIdx.x & 63, rg = threadIdx.x >> 6;
    float s=0.f, s2=0.f;
    for (int r=rg; r<1024; r+=4){ float v = src[(size_t)r*F + f0+fi]; s+=v; s2+=v*v; }
    __shared__ float ls[4][64], ls2[4][64];
    ls[rg][fi]=s; ls2[rg][fi]=s2; __syncthreads();
    if (rg==0){
        float Sv = ls[0][fi]+ls[1][fi]+ls[2][fi]+ls[3][fi];
        float S2 = ls2[0][fi]+ls2[1][fi]+ls2[2][fi]+ls2[3][fi];
        float m  = Sv*(1.f/1024.f);
        float var = S2*(1.f/1024.f) - m*m;
        float sc = g[f0+fi] * rsqrtf(var + 1e-5f);
        scale[f0+fi]=sc;
        shift[f0+fi]=be[f0+fi] - m*sc;
    }
}

// ---------------- legacy bn2 + relu + mean over N (fallback path) ----------------
__global__ void feat_v10(const float* __restrict__ h4, const float* __restrict__ sc,
                         const float* __restrict__ sh, float* __restrict__ feat){
    int b = blockIdx.x, t = threadIdx.x;
    float s = sc[t], o = sh[t], acc = 0.f;
    for (int n=0; n<512; ++n){
        float v = h4[(size_t)(b*512+n)*128 + t]*s + o;
        acc += fmaxf(v, 0.f);
    }
    feat[b*128+t] = acc*(1.f/512.f);
}

// ---------------- classifier ----------------
__global__ void cls_v10(const float* __restrict__ feat, const float* __restrict__ cls_w,
                        const float* __restrict__ cls_b, float* __restrict__ out){
    int t = threadIdx.x;
    if (t < 20){
        int b = t/10, c = t%10;
        float acc = cls_b[c];
        for (int o=0; o<128; ++o)
            acc += feat[b*128+o]*cls_w[c*128+o];
        out[t] = acc;
    }
}

// ---------------- launch ----------------
extern "C" void kernel_launch(void* const* d_in, const int* in_sizes, int n_in,
                              void* d_out, int out_size, void* d_ws, size_t ws_size,
                              hipStream_t stream){
    (void)in_sizes; (void)n_in; (void)out_size;
    const float* x     = (const float*)d_in[0];
    const float* Wg    = (const float*)d_in[1];
    const float* attn  = (const float*)d_in[2];
    const float* W1    = (const float*)d_in[3];
    const float* b1    = (const float*)d_in[4];
    const float* w2    = (const float*)d_in[5];
    const float* b2    = (const float*)d_in[6];
    const float* gc1_w = (const float*)d_in[7];
    const float* gc1_b = (const float*)d_in[8];
    const float* bn1_g = (const float*)d_in[9];
    const float* bn1_b = (const float*)d_in[10];
    const float* gc2_w = (const float*)d_in[11];
    const float* gc2_b = (const float*)d_in[12];
    const float* bn2_g = (const float*)d_in[13];
    const float* bn2_b = (const float*)d_in[14];
    const float* cls_w = (const float*)d_in[15];
    const float* cls_b = (const float*)d_in[16];
    float* out = (float*)d_out;

    float *HP, *NF, *U, *PI, *PJT, *H1, *H2, *H3, *H4;
    float *STAT, *BN1S, *BN1H, *BN2S, *BN2H, *FEAT;
    float *SIbuf = nullptr, *SJbuf = nullptr, *PJ = nullptr, *ALP = nullptr;
    float *PSb = nullptr, *PS2b = nullptr, *FEATP = nullptr;
    int wsPath = (ws_size >= (size_t)22*1024*1024);

    if (wsPath){
        float* W = (float*)d_ws;
        HP  = W + 0;        NF  = W + 1048576;  H1 = W + 2097152;
        PI  = W + 3145728;  PJT = W + 3407872;  U  = W + 3670016;
        H2  = W + 4194304;  H3  = W + 4718592;  H4 = W + 5242880;
        BN1S= W + 5374208;  BN1H= W + 5374720;
        BN2S= W + 5375232;  BN2H= W + 5375360;  FEAT = W + 5375488;
        STAT= W + 5400000;
        SIbuf = W + 5500000; SJbuf = W + 5504096;
        PJ  = H2;            // H2 region free until gc1 GEMM; PJ dead by then
        ALP = PI;            // 2,097,152 floats spanning PI..H3 — dead before pipj writes PI
        PSb = W + 5420000; PS2b = W + 5430000; FEATP = W + 5440000;
    } else {
        HP  = (float*)x;
        NF  = (float*)Wg;
        PI  = (float*)x;
        PJT = (float*)x + 262144;
        U   = (float*)W1;
        H1  = (float*)x;
        H2  = (float*)Wg;
        H3  = (float*)gc1_w;
        H4  = (float*)x;
        STAT= (float*)x;
        float* A = (float*)attn;
        BN1S = A+8;    BN1H = A+520;
        BN2S = A+1032; BN2H = A+1160;  FEAT = A+1288;
    }
    float*    S    = STAT+2;
    float*    CS   = STAT+4;
    unsigned* KC   = (unsigned*)(STAT+6);
    unsigned* PFX  = (unsigned*)(STAT+8);
    unsigned* RANK = (unsigned*)(STAT+10);
    float*    THR  = STAT+12;
    float*    DINV = STAT+14;
    unsigned* H0   = (unsigned*)(STAT+16);
    unsigned* Hh1  = (unsigned*)(STAT+16+4096);
    unsigned* Hh2  = (unsigned*)(STAT+16+8192);

    if (wsPath){
        // nt#1: K-split=2, partial kz=1 -> H1 region (dead), fold into HP
        gemm64_nt<<<dim3(16,16,2),256,0,stream>>>(x, Wg, HP, 512, 1024, 1024, 1024,
                                                  nullptr, nullptr, nullptr, nullptr,
                                                  2, (long)(H1-HP));
        foldk<<<1024,256,0,stream>>>(HP, HP, (long)(H1-HP), 2, 262144);
        sij_v14 <<<64,256,0,stream>>>(HP, attn, SIbuf, SJbuf);
        asm_v17 <<<256,512,0,stream>>>(SIbuf, SJbuf, ALP);
        // PV as batched GEMM: nf[bh] = ALP[bh] @ hp[bh]  (bhmode addressing)
        gemm64_nn<<<dim3(4,8,8),256,0,stream>>>(ALP, HP, NF, 512, 512, 1024, 1024,
                                                262144, 524288, 524288, nullptr, nullptr,
                                                1, 1, 0);
        // pipj: K-split=2. PI partial1 -> PJT region; PJ(=H2) partial1 -> H2+262144.
        gemm64_nt<<<dim3(4,16,4),256,0,stream>>>(NF, W1, PI, 512, 1024, 2048, 256,
                                                 b1, W1+1024, PJ, nullptr,
                                                 2, 262144);
        foldk<<<256,256,0,stream>>>(PI, PI, 262144, 2, 65536);
        foldk<<<256,256,0,stream>>>(PJ, PJ, 262144, 2, 65536);
        transp_v15<<<dim3(4,8,2),256,0,stream>>>(PJ, PJT);
    } else {
        gemm_x_v12<<<256,256,0,stream>>>(x, Wg, HP);
        attn_v12  <<<512,256,0,stream>>>(HP, attn, NF);
        pipj_v13  <<<dim3(4,1,64),256,0,stream>>>(NF, W1, b1, PI, PJT);
    }
    edge_v10  <<<512,256,0,stream>>>(PI, PJT, w2, b2, U);
    hipMemsetAsync(STAT, 0, 10256*sizeof(float), stream);
    k_exp_v13 <<<512,256,0,stream>>>(U, S);
    k_hist_v11<<<128,256,0,stream>>>(U, H0, nullptr, 0, 21, 0x7FFu, 2048);
    k_scan_v11<<<1,512,0,stream>>>(H0, 2048, PFX, RANK, 11, 1, nullptr);
    k_hist_v11<<<128,256,0,stream>>>(U, Hh1, PFX, 21, 10, 0x7FFu, 2048);
    k_scan_v11<<<1,512,0,stream>>>(Hh1, 2048, PFX, RANK, 11, 0, nullptr);
    k_hist_v11<<<128,256,0,stream>>>(U, Hh2, PFX, 10, 0, 0x3FFu, 1024);
    k_scan_v11<<<1,512,0,stream>>>(Hh2, 1024, PFX, RANK, 10, 0, THR);
    k_csum_v11<<<128,256,0,stream>>>(U, THR, CS, KC);
    k_fin_v11 <<<1,64,0,stream>>>(S, CS, KC, THR, DINV);
    adj_v10   <<<2048,256,0,stream>>>(U, THR, DINV);           // U now holds adj

    if (wsPath){
        // nn#1: K-split=2, partials kz=1 -> HP region (dead), fold into H1
        gemm64_nn<<<dim3(16,8,4),256,0,stream>>>(U, NF, H1, 256, 512, 1024, 1024,
                                                 262144, 524288, 524288, nullptr, nullptr,
                                                 0, 2, (long)(HP-H1));
        foldk<<<1024,256,0,stream>>>(H1, H1, (long)(HP-H1), 2, 262144);
        // gc1: K-split=2, partial kz=1 -> NF region (dead), fold into H2
        gemm64_nt<<<dim3(8,16,2),256,0,stream>>>(H1, gc1_w, H2, 512, 1024, 1024, 512,
                                                 gc1_b, nullptr, nullptr, nullptr,
                                                 2, (long)(NF-H2));
        foldk<<<512,256,0,stream>>>(H2, H2, (long)(NF-H2), 2, 131072);
        bnp1<<<dim3(8,16),256,0,stream>>>(H2, PSb, PS2b, 512);
        bnp2<<<8,64,0,stream>>>(PSb, PS2b, bn1_g, bn1_b, BN1S, BN1H, 512);
        // nn#2: K-split=2, partial kz=1 -> HP region, fold into H3
        gemm64_nn<<<dim3(8,8,4),256,0,stream>>>(U, H2, H3, 256, 512, 512, 512,
                                                262144, 262144, 262144, BN1S, BN1H,
                                                0, 2, (long)(HP-H3));
        foldk<<<512,256,0,stream>>>(H3, H3, (long)(HP-H3), 2, 131072);
        // gc2: K-split=4 partials into HP region, fold into H4
        gemm64_nt<<<dim3(2,16,4),256,0,stream>>>(H3, gc2_w, HP, 128, 512, 512, 128,
                                                 gc2_b, nullptr, nullptr, nullptr,
                                                 4, 131072);
        foldk<<<128,256,0,stream>>>(H4, HP, 131072, 4, 32768);
        bnp1<<<dim3(2,16),256,0,stream>>>(H4, PSb, PS2b, 128);
        bnp2<<<2,64,0,stream>>>(PSb, PS2b, bn2_g, bn2_b, BN2S, BN2H, 128);
        feat_p<<<dim3(2,8),128,0,stream>>>(H4, BN2S, BN2H, FEATP);
        feat_f<<<2,128,0,stream>>>(FEATP, FEAT);
    } else {
        gemm_nn32 <<<dim3(16,16,2),256,0,stream>>>(U, NF, H1, 512, 512, 1024, 1024,
                                                   262144, 524288, 524288, nullptr, nullptr);
        gemm_nt32 <<<dim3(8,32),256,0,stream>>>(H1, gc1_w, H2, 1024, 1024, 1024, 512, gc1_b);
        bnstats_v10<<<8,256,0,stream>>>(H2, bn1_g, bn1_b, BN1S, BN1H, 512);
        gemm_nn32 <<<dim3(8,16,2),256,0,stream>>>(U, H2, H3, 512, 512, 512, 512,
                                                  262144, 262144, 262144, BN1S, BN1H);
        gemm_nt32 <<<dim3(2,32),256,0,stream>>>(H3, gc2_w, H4, 512, 512, 512, 128, gc2_b);
        bnstats_v10<<<2,256,0,stream>>>(H4, bn2_g, bn2_b, BN2S, BN2H, 128);
        feat_v10  <<<2,128,0,stream>>>(H4, BN2S, BN2H, FEAT);
    }
    cls_v10   <<<1,64,0,stream>>>(FEAT, cls_w, cls_b, out);
}

// Round 9
// 364.329 us; speedup vs baseline: 1.6065x; 1.0230x over previous
//
#include <hip/hip_runtime.h>
#include <hip/hip_bf16.h>

// B=2, N=512, FDIM=1024, HEADS=4, DH=256, AH=256, HID=512, OUT=128, NCLS=10
// NN=262144, rank = 52429. Inputs fp32, output fp32[20].

// ================= 64x64 fp32 GEMM (8x8/lane, wave-private k-slices) =================
// ksplit>1: z%ksplit = K-chunk -> PARTIAL buffer at C + kz*pstride (normal stores);
//           z/ksplit selects (Bm2,C2,bias2). Partials summed by foldk afterwards.
__global__ __launch_bounds__(256) void gemm64_nt(
    const float* __restrict__ A, const float* __restrict__ Bm, float* __restrict__ C,
    int K, int lda, int ldb, int ldc, const float* __restrict__ bias,
    const float* __restrict__ Bm2, float* __restrict__ C2, const float* __restrict__ bias2,
    int ksplit, long pstride)
{
    if (ksplit > 1){
        int z = blockIdx.z;
        int kz = z % ksplit;
        if (z / ksplit){ Bm = Bm2; C = C2; bias = bias2; }
        A += (size_t)kz * K; Bm += (size_t)kz * K;
        C += (long)kz * pstride;
        if (kz) bias = nullptr;
    } else if (blockIdx.z){
        Bm = Bm2; C = C2; bias = bias2;
    }
    __shared__ float As[64][64], Bs[64][64];
    int t = threadIdx.x;
    int m0 = blockIdx.y*64, n0 = blockIdx.x*64;
    int w = t>>6, lane = t&63;
    int mi = lane>>3, ni = lane&7;
    int kc = w*16;                            // wave's private k-slice in the tile
    const float* Ar = A + (size_t)(m0+lane)*lda + kc;
    const float* Br = Bm + (size_t)(n0+lane)*ldb + kc;
    float4 pa[4], pb[4];
    #pragma unroll
    for (int j=0;j<4;++j){ pa[j]=*(const float4*)(Ar+j*4); pb[j]=*(const float4*)(Br+j*4); }
    float acc[8][8] = {};
    for (int k0=0; k0<K; k0+=64){
        #pragma unroll
        for (int j=0;j<4;++j){
            As[kc+j*4+0][lane]=pa[j].x; As[kc+j*4+1][lane]=pa[j].y;
            As[kc+j*4+2][lane]=pa[j].z; As[kc+j*4+3][lane]=pa[j].w;
            Bs[kc+j*4+0][lane]=pb[j].x; Bs[kc+j*4+1][lane]=pb[j].y;
            Bs[kc+j*4+2][lane]=pb[j].z; Bs[kc+j*4+3][lane]=pb[j].w;
        }
        if (k0+64 < K){
            #pragma unroll
            for (int j=0;j<4;++j){
                pa[j]=*(const float4*)(Ar+k0+64+j*4);
                pb[j]=*(const float4*)(Br+k0+64+j*4);
            }
        }
        #pragma unroll
        for (int kk=0; kk<16; ++kk){
            float4 a0=*(const float4*)&As[kc+kk][mi*8], a1=*(const float4*)&As[kc+kk][mi*8+4];
            float4 b0=*(const float4*)&Bs[kc+kk][ni*8], b1=*(const float4*)&Bs[kc+kk][ni*8+4];
            float am[8]={a0.x,a0.y,a0.z,a0.w,a1.x,a1.y,a1.z,a1.w};
            float bn[8]={b0.x,b0.y,b0.z,b0.w,b1.x,b1.y,b1.z,b1.w};
            #pragma unroll
            for (int i=0;i<8;++i)
                #pragma unroll
                for (int j2=0;j2<8;++j2) acc[i][j2] += am[i]*bn[j2];
        }
    }
    // ---- reduce 4 wave k-partials through LDS (reuse As/Bs as scratch) ----
    __syncthreads();
    float* s0 = &As[0][0]; float* s1 = &Bs[0][0];
    if (w>=2){
        float* d = (w==2)? s0 : s1;
        #pragma unroll
        for (int i=0;i<8;++i){
            *(float4*)&d[(mi*8+i)*64+ni*8]   = make_float4(acc[i][0],acc[i][1],acc[i][2],acc[i][3]);
            *(float4*)&d[(mi*8+i)*64+ni*8+4] = make_float4(acc[i][4],acc[i][5],acc[i][6],acc[i][7]);
        }
    }
    __syncthreads();
    if (w<2){
        const float* sv = (w==0)? s0 : s1;
        #pragma unroll
        for (int i=0;i<8;++i){
            float4 v0=*(const float4*)&sv[(mi*8+i)*64+ni*8];
            float4 v1=*(const float4*)&sv[(mi*8+i)*64+ni*8+4];
            acc[i][0]+=v0.x; acc[i][1]+=v0.y; acc[i][2]+=v0.z; acc[i][3]+=v0.w;
            acc[i][4]+=v1.x; acc[i][5]+=v1.y; acc[i][6]+=v1.z; acc[i][7]+=v1.w;
        }
    }
    __syncthreads();
    if (w==1){
        #pragma unroll
        for (int i=0;i<8;++i){
            *(float4*)&s0[(mi*8+i)*64+ni*8]   = make_float4(acc[i][0],acc[i][1],acc[i][2],acc[i][3]);
            *(float4*)&s0[(mi*8+i)*64+ni*8+4] = make_float4(acc[i][4],acc[i][5],acc[i][6],acc[i][7]);
        }
    }
    __syncthreads();
    if (w==0){
        #pragma unroll
        for (int i=0;i<8;++i){
            float4 v0=*(const float4*)&s0[(mi*8+i)*64+ni*8];
            float4 v1=*(const float4*)&s0[(mi*8+i)*64+ni*8+4];
            acc[i][0]+=v0.x; acc[i][1]+=v0.y; acc[i][2]+=v0.z; acc[i][3]+=v0.w;
            acc[i][4]+=v1.x; acc[i][5]+=v1.y; acc[i][6]+=v1.z; acc[i][7]+=v1.w;
        }
        float bb[8];
        #pragma unroll
        for (int j2=0;j2<8;++j2) bb[j2] = bias ? bias[n0+ni*8+j2] : 0.f;
        #pragma unroll
        for (int i=0;i<8;++i){
            *(float4*)&C[(size_t)(m0+mi*8+i)*ldc + n0+ni*8]   =
                make_float4(acc[i][0]+bb[0],acc[i][1]+bb[1],acc[i][2]+bb[2],acc[i][3]+bb[3]);
            *(float4*)&C[(size_t)(m0+mi*8+i)*ldc + n0+ni*8+4] =
                make_float4(acc[i][4]+bb[4],acc[i][5]+bb[5],acc[i][6]+bb[6],acc[i][7]+bb[7]);
        }
    }
}

// NN batched: C[m][n] = sum_k A[m][k]*B[k][n], optional bn-relu fused on B columns.
// bhmode: z -> b=z>>2,h=z&3; B/C offset = b*sB + h*256 (attention PV addressing).
// ksplit>1 (non-bhmode): z = bz*ksplit + kz; partial at C + bz*sC + kz*pstride.
__global__ __launch_bounds__(256) void gemm64_nn(
    const float* __restrict__ A, const float* __restrict__ Bm, float* __restrict__ C,
    int K, int lda, int ldb, int ldc, long sA, long sB, long sC,
    const float* __restrict__ bsc, const float* __restrict__ bsh, int bhmode,
    int ksplit, long pstride)
{
    if (bhmode){
        int z = blockIdx.z;
        A  += (size_t)z*sA;
        Bm += (size_t)(z>>2)*sB + (size_t)(z&3)*256;
        C  += (size_t)(z>>2)*sC + (size_t)(z&3)*256;
    } else {
        int z = blockIdx.z;
        int bz = z, kz = 0;
        if (ksplit > 1){ bz = z / ksplit; kz = z % ksplit; }
        A  += (long)bz*sA + (size_t)kz*K;
        Bm += (long)bz*sB + (size_t)kz*K*ldb;
        C  += (long)bz*sC + (long)kz*pstride;
    }
    __shared__ float As[64][64], Bs[64][64];
    int t=threadIdx.x, w=t>>6, lane=t&63;
    int m0=blockIdx.y*64, n0=blockIdx.x*64;
    int mi=lane>>3, ni=lane&7;
    int kc=w*16;
    const float* Ar = A + (size_t)(m0+lane)*lda + kc;
    int kr = lane>>4, nc = (lane&15)*4;
    const float* Br = Bm + (size_t)(kc+kr)*ldb + n0 + nc;
    float4 sc4 = make_float4(1,1,1,1), sh4 = make_float4(0,0,0,0);
    if (bsc){ sc4 = *(const float4*)&bsc[n0+nc]; sh4 = *(const float4*)&bsh[n0+nc]; }
    float4 pa[4], pb[4];
    #pragma unroll
    for (int j=0;j<4;++j){
        pa[j]=*(const float4*)(Ar+j*4);
        pb[j]=*(const float4*)(Br + (size_t)(j*4)*ldb);
    }
    float acc[8][8] = {};
    for (int k0=0; k0<K; k0+=64){
        #pragma unroll
        for (int j=0;j<4;++j){
            As[kc+j*4+0][lane]=pa[j].x; As[kc+j*4+1][lane]=pa[j].y;
            As[kc+j*4+2][lane]=pa[j].z; As[kc+j*4+3][lane]=pa[j].w;
            float4 bv = pb[j];
            if (bsc){
                bv.x=fmaxf(bv.x*sc4.x+sh4.x,0.f); bv.y=fmaxf(bv.y*sc4.y+sh4.y,0.f);
                bv.z=fmaxf(bv.z*sc4.z+sh4.z,0.f); bv.w=fmaxf(bv.w*sc4.w+sh4.w,0.f);
            }
            *(float4*)&Bs[kc+kr+j*4][nc] = bv;
        }
        if (k0+64 < K){
            #pragma unroll
            for (int j=0;j<4;++j){
                pa[j]=*(const float4*)(Ar+k0+64+j*4);
                pb[j]=*(const float4*)(Br + (size_t)(k0+64+j*4)*ldb);
            }
        }
        #pragma unroll
        for (int kk=0; kk<16; ++kk){
            float4 a0=*(const float4*)&As[kc+kk][mi*8], a1=*(const float4*)&As[kc+kk][mi*8+4];
            float4 b0=*(const float4*)&Bs[kc+kk][ni*8], b1=*(const float4*)&Bs[kc+kk][ni*8+4];
            float am[8]={a0.x,a0.y,a0.z,a0.w,a1.x,a1.y,a1.z,a1.w};
            float bn[8]={b0.x,b0.y,b0.z,b0.w,b1.x,b1.y,b1.z,b1.w};
            #pragma unroll
            for (int i=0;i<8;++i)
                #pragma unroll
                for (int j2=0;j2<8;++j2) acc[i][j2] += am[i]*bn[j2];
        }
    }
    __syncthreads();
    float* s0 = &As[0][0]; float* s1 = &Bs[0][0];
    if (w>=2){
        float* d = (w==2)? s0 : s1;
        #pragma unroll
        for (int i=0;i<8;++i){
            *(float4*)&d[(mi*8+i)*64+ni*8]   = make_float4(acc[i][0],acc[i][1],acc[i][2],acc[i][3]);
            *(float4*)&d[(mi*8+i)*64+ni*8+4] = make_float4(acc[i][4],acc[i][5],acc[i][6],acc[i][7]);
        }
    }
    __syncthreads();
    if (w<2){
        const float* sv = (w==0)? s0 : s1;
        #pragma unroll
        for (int i=0;i<8;++i){
            float4 v0=*(const float4*)&sv[(mi*8+i)*64+ni*8];
            float4 v1=*(const float4*)&sv[(mi*8+i)*64+ni*8+4];
            acc[i][0]+=v0.x; acc[i][1]+=v0.y; acc[i][2]+=v0.z; acc[i][3]+=v0.w;
            acc[i][4]+=v1.x; acc[i][5]+=v1.y; acc[i][6]+=v1.z; acc[i][7]+=v1.w;
        }
    }
    __syncthreads();
    if (w==1){
        #pragma unroll
        for (int i=0;i<8;++i){
            *(float4*)&s0[(mi*8+i)*64+ni*8]   = make_float4(acc[i][0],acc[i][1],acc[i][2],acc[i][3]);
            *(float4*)&s0[(mi*8+i)*64+ni*8+4] = make_float4(acc[i][4],acc[i][5],acc[i][6],acc[i][7]);
        }
    }
    __syncthreads();
    if (w==0){
        #pragma unroll
        for (int i=0;i<8;++i){
            float4 v0=*(const float4*)&s0[(mi*8+i)*64+ni*8];
            float4 v1=*(const float4*)&s0[(mi*8+i)*64+ni*8+4];
            acc[i][0]+=v0.x; acc[i][1]+=v0.y; acc[i][2]+=v0.z; acc[i][3]+=v0.w;
            acc[i][4]+=v1.x; acc[i][5]+=v1.y; acc[i][6]+=v1.z; acc[i][7]+=v1.w;
        }
        #pragma unroll
        for (int i=0;i<8;++i){
            *(float4*)&C[(size_t)(m0+mi*8+i)*ldc + n0+ni*8]   =
                make_float4(acc[i][0],acc[i][1],acc[i][2],acc[i][3]);
            *(float4*)&C[(size_t)(m0+mi*8+i)*ldc + n0+ni*8+4] =
                make_float4(acc[i][4],acc[i][5],acc[i][6],acc[i][7]);
        }
    }
}

// ---------------- fold k partials: dst[i] = sum_{p<k} src[p*pstride + i] ----------------
__global__ void foldk(float* __restrict__ dst, const float* __restrict__ src,
                      long pstride, int kparts, int n4){
    int i = blockIdx.x*256 + threadIdx.x;
    if (i < n4){
        float4 s = *(const float4*)&src[(size_t)i*4];
        for (int p=1;p<kparts;++p){
            float4 v = *(const float4*)&src[(long)p*pstride + (size_t)i*4];
            s.x+=v.x; s.y+=v.y; s.z+=v.z; s.w+=v.w;
        }
        *(float4*)&dst[(size_t)i*4] = s;
    }
}

// ---------------- PJ (1024x256) -> pjT[b][a][n] transpose via LDS ----------------
__global__ void transp_v15(const float* __restrict__ PJ, float* __restrict__ pjT){
    __shared__ float T[64][68];
    int b = blockIdx.z;
    int a0 = blockIdx.x*64, n0 = blockIdx.y*64;
    int t = threadIdx.x;
    int c = t&15, r = t>>4;
    for (int rr=r; rr<64; rr+=16){
        float4 v = *(const float4*)&PJ[(size_t)(b*512+n0+rr)*256 + a0 + c*4];
        T[rr][c*4]=v.x; T[rr][c*4+1]=v.y; T[rr][c*4+2]=v.z; T[rr][c*4+3]=v.w;
    }
    __syncthreads();
    for (int rr=r; rr<64; rr+=16){
        float4 o = make_float4(T[c*4][rr], T[c*4+1][rr], T[c*4+2][rr], T[c*4+3][rr]);
        *(float4*)&pjT[(size_t)b*131072 + (size_t)(a0+rr)*512 + n0 + c*4] = o;
    }
}

// ---------------- parallel batchnorm stats: stage1 (64 rows x 64 feats per block) ------
__global__ void bnp1(const float* __restrict__ src, float* __restrict__ PS,
                     float* __restrict__ PS2, int F){
    int f0 = blockIdx.x*64, r0 = blockIdx.y*64;
    int fi = threadIdx.x & 63, rg = threadIdx.x >> 6;
    float s=0.f, s2=0.f;
    #pragma unroll
    for (int i=0;i<16;++i){
        float v = src[(size_t)(r0+rg+i*4)*F + f0+fi];
        s += v; s2 += v*v;
    }
    __shared__ float ls[4][64], ls2[4][64];
    ls[rg][fi]=s; ls2[rg][fi]=s2; __syncthreads();
    if (rg==0){
        PS [blockIdx.y*F + f0+fi] = ls[0][fi]+ls[1][fi]+ls[2][fi]+ls[3][fi];
        PS2[blockIdx.y*F + f0+fi] = ls2[0][fi]+ls2[1][fi]+ls2[2][fi]+ls2[3][fi];
    }
}

// ---------------- stage2: fold 16 chunks, produce scale/shift ----------------
__global__ void bnp2(const float* __restrict__ PS, const float* __restrict__ PS2,
                     const float* __restrict__ g, const float* __restrict__ be,
                     float* __restrict__ scale, float* __restrict__ shift, int F){
    int f = blockIdx.x*64 + threadIdx.x;
    float S=0.f, S2=0.f;
    #pragma unroll
    for (int c=0;c<16;++c){ S += PS[c*F+f]; S2 += PS2[c*F+f]; }
    float m  = S*(1.f/1024.f);
    float var = S2*(1.f/1024.f) - m*m;
    float sc = g[f] * rsqrtf(var + 1e-5f);
    scale[f]=sc; shift[f]=be[f] - m*sc;
}

// ---------------- parallel bn2+relu+mean: stage1 (64 rows per block) ----------------
__global__ void feat_p(const float* __restrict__ h4, const float* __restrict__ sc,
                       const float* __restrict__ sh, float* __restrict__ featp){
    int b = blockIdx.x, chunk = blockIdx.y;
    int t = threadIdx.x;              // 128
    float s = sc[t], o = sh[t], acc = 0.f;
    int n0 = chunk*64;
    #pragma unroll
    for (int i=0;i<64;++i){
        float v = h4[(size_t)(b*512+n0+i)*128 + t]*s + o;
        acc += fmaxf(v, 0.f);
    }
    featp[(b*8+chunk)*128 + t] = acc;
}

__global__ void feat_f(const float* __restrict__ featp, float* __restrict__ feat){
    int b = blockIdx.x, t = threadIdx.x;
    float a = 0.f;
    #pragma unroll
    for (int c=0;c<8;++c) a += featp[(b*8+c)*128 + t];
    feat[b*128+t] = a*(1.f/512.f);
}

// ================= legacy kernels (fallback non-ws path) =================
__global__ void gemm_nn32(const float* __restrict__ A, const float* __restrict__ Bm,
                          float* __restrict__ C, int K, int lda, int ldb, int ldc,
                          long sA, long sB, long sC,
                          const float* __restrict__ bsc, const float* __restrict__ bsh){
    A  += (long)blockIdx.z * sA;
    Bm += (long)blockIdx.z * sB;
    C  += (long)blockIdx.z * sC;
    __shared__ float As[16][32], Bs[16][64];
    int n0 = blockIdx.x*64, m0 = blockIdx.y*32;
    int t = threadIdx.x, tx = t & 15, ty = t >> 4;
    int sr = t >> 3, sk = (t & 7)*2;
    int bk = t >> 4, bn4 = (t & 15)*4;
    float acc[2][4] = {};
    for (int k0=0; k0<K; k0+=16){
        #pragma unroll
        for (int i=0;i<2;++i) As[sk+i][sr] = A[(size_t)(m0+sr)*lda + k0+sk+i];
        float4 bv = *(const float4*)&Bm[(size_t)(k0+bk)*ldb + n0+bn4];
        if (bsc){
            bv.x = fmaxf(bv.x*bsc[n0+bn4+0]+bsh[n0+bn4+0], 0.f);
            bv.y = fmaxf(bv.y*bsc[n0+bn4+1]+bsh[n0+bn4+1], 0.f);
            bv.z = fmaxf(bv.z*bsc[n0+bn4+2]+bsh[n0+bn4+2], 0.f);
            bv.w = fmaxf(bv.w*bsc[n0+bn4+3]+bsh[n0+bn4+3], 0.f);
        }
        *(float4*)&Bs[bk][bn4] = bv;
        __syncthreads();
        #pragma unroll
        for (int k=0;k<16;++k){
            float a0 = As[k][ty*2], a1 = As[k][ty*2+1];
            float4 b = *(const float4*)&Bs[k][tx*4];
            acc[0][0]+=a0*b.x; acc[0][1]+=a0*b.y; acc[0][2]+=a0*b.z; acc[0][3]+=a0*b.w;
            acc[1][0]+=a1*b.x; acc[1][1]+=a1*b.y; acc[1][2]+=a1*b.z; acc[1][3]+=a1*b.w;
        }
        __syncthreads();
    }
    #pragma unroll
    for (int i=0;i<2;++i){
        float4 v = make_float4(acc[i][0],acc[i][1],acc[i][2],acc[i][3]);
        *(float4*)&C[(size_t)(m0+ty*2+i)*ldc + n0+tx*4] = v;
    }
}

__global__ void gemm_nt32(const float* __restrict__ A, const float* __restrict__ Bm,
                          float* __restrict__ C, int K, int lda, int ldb, int ldc,
                          const float* __restrict__ bias){
    __shared__ float As[16][32], Bs[16][64];
    int n0 = blockIdx.x*64, m0 = blockIdx.y*32;
    int t = threadIdx.x, tx = t & 15, ty = t >> 4;
    int sr = t >> 3, sk = (t & 7)*2;
    int bn = t >> 2, bkk = (t & 3)*4;         // B^T staging: row bn, 4 k's
    float acc[2][4] = {};
    for (int k0=0; k0<K; k0+=16){
        #pragma unroll
        for (int i=0;i<2;++i) As[sk+i][sr] = A[(size_t)(m0+sr)*lda + k0+sk+i];
        float4 wv = *(const float4*)&Bm[(size_t)(n0+bn)*ldb + k0+bkk];
        Bs[bkk+0][bn]=wv.x; Bs[bkk+1][bn]=wv.y; Bs[bkk+2][bn]=wv.z; Bs[bkk+3][bn]=wv.w;
        __syncthreads();
        #pragma unroll
        for (int k=0;k<16;++k){
            float a0 = As[k][ty*2], a1 = As[k][ty*2+1];
            float4 b = *(const float4*)&Bs[k][tx*4];
            acc[0][0]+=a0*b.x; acc[0][1]+=a0*b.y; acc[0][2]+=a0*b.z; acc[0][3]+=a0*b.w;
            acc[1][0]+=a1*b.x; acc[1][1]+=a1*b.y; acc[1][2]+=a1*b.z; acc[1][3]+=a1*b.w;
        }
        __syncthreads();
    }
    float4 bb = bias ? *(const float4*)&bias[n0+tx*4] : make_float4(0,0,0,0);
    #pragma unroll
    for (int i=0;i<2;++i){
        float4 v = make_float4(acc[i][0]+bb.x,acc[i][1]+bb.y,acc[i][2]+bb.z,acc[i][3]+bb.w);
        *(float4*)&C[(size_t)(m0+ty*2+i)*ldc + n0+tx*4] = v;
    }
}

__global__ void gemm_x_v12(const float* __restrict__ X, const float* __restrict__ Wg,
                           float* __restrict__ dst){
    __shared__ float xs[4][1024];
    int m0 = blockIdx.x*4;
    int t = threadIdx.x;
    for (int i=t;i<4096;i+=256){ int r=i>>10, c=i&1023; xs[r][c]=X[(size_t)(m0+r)*1024+c]; }
    __syncthreads();
    const float* w0 = Wg + (size_t)(t*4)*1024;
    float acc[4][4] = {};
    for (int k0=0;k0<1024;k0+=16){
        float4 xv[4][4];
        #pragma unroll
        for (int r=0;r<4;++r)
            #pragma unroll
            for (int c=0;c<4;++c) xv[r][c] = *(const float4*)&xs[r][k0+4*c];
        #pragma unroll
        for (int j=0;j<4;++j){
            const float* wr = w0 + (size_t)j*1024 + k0;
            #pragma unroll
            for (int c=0;c<4;++c){
                float4 w = *(const float4*)(wr + 4*c);
                #pragma unroll
                for (int r=0;r<4;++r)
                    acc[r][j] += xv[r][c].x*w.x + xv[r][c].y*w.y
                               + xv[r][c].z*w.z + xv[r][c].w*w.w;
            }
        }
    }
    int n0 = t*4;
    #pragma unroll
    for (int r=0;r<4;++r){
        float4 v = make_float4(acc[r][0],acc[r][1],acc[r][2],acc[r][3]);
        *(float4*)&dst[(size_t)(m0+r)*1024 + n0] = v;
    }
}

__global__ void attn_v12(const float* __restrict__ hp, const float* __restrict__ attn,
                         float* __restrict__ nf){
    int blk = blockIdx.x;
    int bh = blk >> 6, i0 = (blk & 63)*8;
    int b = bh >> 2, h = bh & 3;
    int t = threadIdx.x;
    __shared__ float ais[256], ajs[256], sjs[512], sis[8], inv[8];
    __shared__ float alpha[8][512];
    __shared__ float red[256];
    ais[t] = attn[h*512 + t];
    ajs[t] = attn[h*512 + 256 + t];
    __syncthreads();
    const float* hpb = hp + (size_t)b*524288 + h*256;
    for (int j=t; j<512; j+=256){
        const float* row = hpb + (size_t)j*1024;
        float s=0.f;
        for (int d=0; d<256; ++d) s += row[d]*ajs[d];
        sjs[j]=s;
    }
    if (t<8){
        const float* row = hpb + (size_t)(i0+t)*1024;
        float s=0.f;
        for (int d=0; d<256; ++d) s += row[d]*ais[d];
        sis[t]=s;
    }
    __syncthreads();
    for (int ii=0; ii<8; ++ii){
        float si = sis[ii];
        float e0 = si + sjs[t], e1 = si + sjs[t+256];
        e0 = (e0>=0.f)? e0 : 0.2f*e0;
        e1 = (e1>=0.f)? e1 : 0.2f*e1;
        float p0 = expf(e0), p1 = expf(e1);
        alpha[ii][t]=p0; alpha[ii][t+256]=p1;
        red[t]=p0+p1; __syncthreads();
        for (int s=128; s>0; s>>=1){ if (t<s) red[t]+=red[t+s]; __syncthreads(); }
        if (t==0) inv[ii] = 1.0f/red[0];
        __syncthreads();
    }
    float acc[8] = {};
    for (int j=0; j<512; ++j){
        float r = hpb[(size_t)j*1024 + t];
        #pragma unroll
        for (int ii=0; ii<8; ++ii) acc[ii] += alpha[ii][j]*r;
    }
    #pragma unroll
    for (int ii=0; ii<8; ++ii)
        nf[(size_t)(b*512+i0+ii)*1024 + h*256 + t] = acc[ii]*inv[ii];
}

// ---------------- s_i / s_j precompute ----------------
__global__ void sij_v14(const float* __restrict__ hp, const float* __restrict__ attn,
                        float* __restrict__ SI, float* __restrict__ SJ){
    int t = threadIdx.x;
    int lane = t & 63, w = t >> 6;
    int h  = lane >> 4;
    int e0 = (lane & 15) * 16;
    const float* ai = attn + h*512 + e0;
    const float* aj = ai + 256;
    float4 wi[4], wj[4];
    #pragma unroll
    for (int q=0;q<4;++q){ wi[q] = *(const float4*)(ai + 4*q); wj[q] = *(const float4*)(aj + 4*q); }
    int row0 = blockIdx.x*16 + w*4;
    for (int r=0;r<4;++r){
        int row = row0 + r;
        const float* hr = hp + (size_t)row*1024 + h*256 + e0;
        float si=0.f, sj=0.f;
        #pragma unroll
        for (int q=0;q<4;++q){
            float4 v = *(const float4*)(hr + 4*q);
            si += v.x*wi[q].x + v.y*wi[q].y + v.z*wi[q].z + v.w*wi[q].w;
            sj += v.x*wj[q].x + v.y*wj[q].y + v.z*wj[q].z + v.w*wj[q].w;
        }
        #pragma unroll
        for (int s=1;s<16;s<<=1){
            si += __shfl_xor(si, s, 64);
            sj += __shfl_xor(sj, s, 64);
        }
        if ((lane & 15)==0){
            int b = row >> 9, n = row & 511;
            SI[(size_t)(b*4+h)*512 + n] = si;
            SJ[(size_t)(b*4+h)*512 + n] = sj;
        }
    }
}

// ---------------- alpha materialization: exp(leaky(si+sj))*inv -> ALP[bh][i][j] --------
__global__ __launch_bounds__(512) void asm_v17(const float* __restrict__ SI,
                                               const float* __restrict__ SJ,
                                               float* __restrict__ ALP){
    int blk = blockIdx.x;                 // 256 blocks
    int bh = blk >> 5, i0 = (blk & 31)*16;
    int t = threadIdx.x;                  // 512 = all j
    int w = t >> 6, lane = t & 63;
    __shared__ float wsum[8][16];
    __shared__ float inv[16];
    float sj = SJ[(size_t)bh*512 + t];
    const float* sip = SI + (size_t)bh*512 + i0;
    float p[16], part[16];
    #pragma unroll
    for (int ii=0; ii<16; ++ii){
        float e = sip[ii] + sj;
        e = (e>=0.f)? e : 0.2f*e;
        p[ii] = expf(e);
        part[ii] = p[ii];
    }
    #pragma unroll
    for (int s=1;s<64;s<<=1){
        #pragma unroll
        for (int ii=0;ii<16;++ii) part[ii] += __shfl_xor(part[ii], s, 64);
    }
    if (lane==0){
        #pragma unroll
        for (int ii=0;ii<16;++ii) wsum[w][ii] = part[ii];
    }
    __syncthreads();
    if (t<16){
        float s=0.f;
        #pragma unroll
        for (int ww=0;ww<8;++ww) s += wsum[ww][t];
        inv[t] = 1.0f/s;
    }
    __syncthreads();
    float* dst = ALP + (size_t)bh*262144 + (size_t)i0*512 + t;
    #pragma unroll
    for (int ii=0; ii<16; ++ii)
        dst[(size_t)ii*512] = p[ii]*inv[ii];
}

// ---------------- legacy pipj (fallback path) ----------------
__global__ void pipj_v13(const float* __restrict__ nf, const float* __restrict__ W1,
                         const float* __restrict__ b1, float* __restrict__ pi,
                         float* __restrict__ pjT){
    int half = blockIdx.z >> 5;
    int m0 = (blockIdx.z & 31)*32;
    int a0 = blockIdx.x*64;
    __shared__ float As[16][32], Bs[16][64];
    int t = threadIdx.x, tx = t & 15, ty = t >> 4;
    int sr = t >> 3, sk = (t & 7)*2;
    int bn = t >> 2, bkk = (t & 3)*4;
    const float* Wbase = W1 + (half ? 1024 : 0);
    float acc[2][4] = {};
    for (int k0=0; k0<1024; k0+=16){
        #pragma unroll
        for (int i=0;i<2;++i) As[sk+i][sr] = nf[(size_t)(m0+sr)*1024 + k0+sk+i];
        float4 wv = *(const float4*)&Wbase[(size_t)(a0+bn)*2048 + k0+bkk];
        Bs[bkk+0][bn]=wv.x; Bs[bkk+1][bn]=wv.y; Bs[bkk+2][bn]=wv.z; Bs[bkk+3][bn]=wv.w;
        __syncthreads();
        #pragma unroll
        for (int k=0;k<16;++k){
            float a0v = As[k][ty*2], a1v = As[k][ty*2+1];
            float4 b = *(const float4*)&Bs[k][tx*4];
            acc[0][0]+=a0v*b.x; acc[0][1]+=a0v*b.y; acc[0][2]+=a0v*b.z; acc[0][3]+=a0v*b.w;
            acc[1][0]+=a1v*b.x; acc[1][1]+=a1v*b.y; acc[1][2]+=a1v*b.z; acc[1][3]+=a1v*b.w;
        }
        __syncthreads();
    }
    if (!half){
        float4 bb = *(const float4*)&b1[a0+tx*4];
        #pragma unroll
        for (int i=0;i<2;++i){
            float4 v = make_float4(acc[i][0]+bb.x,acc[i][1]+bb.y,acc[i][2]+bb.z,acc[i][3]+bb.w);
            *(float4*)&pi[(size_t)(m0+ty*2+i)*256 + a0+tx*4] = v;
        }
    } else {
        #pragma unroll
        for (int i=0;i<2;++i){
            int m = m0+ty*2+i;
            size_t base = (size_t)(m>>9)*131072 + (m&511);
            #pragma unroll
            for (int j=0;j<4;++j)
                pjT[base + (size_t)(a0+tx*4+j)*512] = acc[i][j];
        }
    }
}

// ---------------- edge scores: 4 query rows per block (halved pjT traffic) -------------
__global__ void edge_v12(const float* __restrict__ pi, const float* __restrict__ pjT,
                         const float* __restrict__ w2, const float* __restrict__ b2,
                         float* __restrict__ es){
    int blk = blockIdx.x;                 // 256 blocks
    int b = blk >> 7, i0 = (blk & 127)*4;
    int t = threadIdx.x;
    __shared__ float pis[4][256], w2s[256];
    w2s[t] = w2[t];
    #pragma unroll
    for (int r=0;r<4;++r)
        pis[r][t] = pi[(size_t)(b*512+i0+r)*256 + t];
    __syncthreads();
    float a0[4]={0,0,0,0}, a1[4]={0,0,0,0};
    const float* pj = pjT + (size_t)b*131072;
    #pragma unroll 4
    for (int a=0; a<256; ++a){
        float pv0 = pj[(size_t)a*512 + t];
        float pv1 = pj[(size_t)a*512 + t + 256];
        float w  = w2s[a];
        #pragma unroll
        for (int r=0;r<4;++r){
            float p = pis[r][a];
            a0[r] += fmaxf(p+pv0, 0.f)*w;
            a1[r] += fmaxf(p+pv1, 0.f)*w;
        }
    }
    float b2f = b2[0];
    #pragma unroll
    for (int r=0;r<4;++r){
        es[(size_t)(b*512+i0+r)*512 + t]       = a0[r] + b2f;
        es[(size_t)(b*512+i0+r)*512 + t + 256] = a1[r] + b2f;
    }
}

// ---------------- exp(2*es) in place + sum + FUSED histogram pass 0 --------------------
__global__ void k_exp_v14(float* __restrict__ u, float* __restrict__ S,
                          unsigned* __restrict__ hist){
    __shared__ unsigned h[2048];
    __shared__ float red[256];
    int t = threadIdx.x;
    for (int i=t;i<2048;i+=256) h[i]=0;
    __syncthreads();
    int b = blockIdx.x >> 8;
    size_t base = (size_t)b*262144 + (size_t)(blockIdx.x & 255)*1024;
    float acc = 0.f;
    for (int i=t;i<1024;i+=256){
        float v = expf(u[base+i]*2.0f);
        u[base+i]=v; acc+=v;
        atomicAdd(&h[(__float_as_uint(v)>>21)&0x7FFu], 1u);
    }
    red[t]=acc; __syncthreads();
    for (int s=128;s>0;s>>=1){ if(t<s) red[t]+=red[t+s]; __syncthreads(); }
    if (t==0) atomicAdd(&S[b], red[0]);
    for (int i=t;i<2048;i+=256) if (h[i]) atomicAdd(&hist[b*2048+i], h[i]);
}

// ---------------- parallel radix histogram (grid 256) ----------------
__global__ void k_hist_v12(const float* __restrict__ u, unsigned* __restrict__ hist,
                           const unsigned* __restrict__ pfx, int cmpShift, int shift,
                           unsigned mask, int nbins){
    __shared__ unsigned h[2048];
    for (int i=threadIdx.x;i<nbins;i+=256) h[i]=0;
    __syncthreads();
    int b = blockIdx.x>>7;
    size_t base = (size_t)b*262144 + (size_t)(blockIdx.x&127)*2048;
    unsigned p = pfx ? pfx[b] : 0u;
    for (int i=threadIdx.x;i<2048;i+=256){
        unsigned bits = __float_as_uint(u[base+i]);
        if (!pfx || (bits>>cmpShift)==p) atomicAdd(&h[(bits>>shift)&mask],1u);
    }
    __syncthreads();
    for (int i=threadIdx.x;i<nbins;i+=256) if (h[i]) atomicAdd(&hist[b*nbins+i], h[i]);
}

// ---------------- scan histogram, descend one level ----------------
__global__ void k_scan_v11(const unsigned* __restrict__ hist, int nbins,
                           unsigned* __restrict__ pfx, unsigned* __restrict__ rank,
                           int passBits, int first, float* __restrict__ thrOut){
    __shared__ unsigned part[2][256];
    int batch = threadIdx.x>>8, lane = threadIdx.x&255;
    int chunk = nbins/256;
    const unsigned* hb = hist + batch*nbins;
    unsigned s=0;
    for (int i=0;i<chunk;++i) s += hb[lane*chunk+i];
    part[batch][lane]=s;
    __syncthreads();
    if (lane==0){
        unsigned r = first ? 52429u : rank[batch];
        unsigned cum=0; int c=0;
        for (;c<256;++c){ unsigned pc=part[batch][c]; if (cum+pc>r) break; cum+=pc; }
        if (c==256) c=255;
        int bin=c*chunk;
        for (int i=0;i<chunk;++i){ unsigned cnt=hb[c*chunk+i]; if (cum+cnt>r){ bin=c*chunk+i; break;} cum+=cnt; }
        rank[batch]=r-cum;
        unsigned np = ((first?0u:pfx[batch])<<passBits) | (unsigned)bin;
        pfx[batch]=np;
        if (thrOut) thrOut[batch]=__uint_as_float(np);
    }
}

// ---------------- parallel kept-sum/count (grid 256) ----------------
__global__ void k_csum_v12(const float* __restrict__ u, const float* __restrict__ THR,
                           float* __restrict__ CS, unsigned* __restrict__ KC){
    int b = blockIdx.x>>7;
    size_t base = (size_t)b*262144 + (size_t)(blockIdx.x&127)*2048;
    float th = THR[b];
    float cs=0.f; unsigned kc=0;
    for (int i=threadIdx.x;i<2048;i+=256){ float v=u[base+i]; if (v>=th){ cs+=v; kc++; } }
    __shared__ float rf[256]; __shared__ unsigned ru[256];
    rf[threadIdx.x]=cs; ru[threadIdx.x]=kc; __syncthreads();
    for (int s=128;s>0;s>>=1){ if(threadIdx.x<s){ rf[threadIdx.x]+=rf[threadIdx.x+s]; ru[threadIdx.x]+=ru[threadIdx.x+s]; } __syncthreads(); }
    if (threadIdx.x==0){ atomicAdd(&CS[b], rf[0]); atomicAdd(&KC[b], ru[0]); }
}

// ---------------- finalize thr/dinv ----------------
__global__ void k_fin_v11(const float* __restrict__ S, const float* __restrict__ CS,
                          const unsigned* __restrict__ KC, float* __restrict__ THR,
                          float* __restrict__ DINV){
    int t = threadIdx.x;
    if (t < 2){
        float ks = CS[t]; float th = THR[t];
        if (KC[t] < 209715u){ th = 0.f; ks = S[t]; }
        THR[t]=th;
        DINV[t]=1.0f/(ks + 1e-12f*S[t]);
    }
}

// ---------------- adjacency, in place over u ----------------
__global__ void adj_v10(float* __restrict__ u, const float* __restrict__ thrU,
                        const float* __restrict__ dinv){
    int idx = blockIdx.x*256 + threadIdx.x;
    int b = idx >> 18;
    float v = u[idx];
    u[idx] = (v >= thrU[b]) ? v*dinv[b] : 0.0f;
}

// ---------------- legacy batchnorm stats (fallback path) ----------------
__global__ void bnstats_v10(const float* __restrict__ src, const float* __restrict__ g,
                            const float* __restrict__ be, float* __restrict__ scale,
                            float* __restrict__ shift, int F){
    int f0 = blockIdx.x*64;
    int fi = threadIdx.x & 63, rg = threadIdx.x >> 6;
    float s=0.f, s2=0.f;
    for (int r=rg; r<1024; r+=4){ float v = src[(size_t)r*F + f0+fi]; s+=v; s2+=v*v; }
    __shared__ float ls[4][64], ls2[4][64];
    ls[rg][fi]=s; ls2[rg][fi]=s2; __syncthreads();
    if (rg==0){
        float Sv = ls[0][fi]+ls[1][fi]+ls[2][fi]+ls[3][fi];
        float S2 = ls2[0][fi]+ls2[1][fi]+ls2[2][fi]+ls2[3][fi];
        float m  = Sv*(1.f/1024.f);
        float var = S2*(1.f/1024.f) - m*m;
        float sc = g[f0+fi] * rsqrtf(var + 1e-5f);
        scale[f0+fi]=sc;
        shift[f0+fi]=be[f0+fi] - m*sc;
    }
}

// ---------------- legacy bn2 + relu + mean over N (fallback path) ----------------
__global__ void feat_v10(const float* __restrict__ h4, const float* __restrict__ sc,
                         const float* __restrict__ sh, float* __restrict__ feat){
    int b = blockIdx.x, t = threadIdx.x;
    float s = sc[t], o = sh[t], acc = 0.f;
    for (int n=0; n<512; ++n){
        float v = h4[(size_t)(b*512+n)*128 + t]*s + o;
        acc += fmaxf(v, 0.f);
    }
    feat[b*128+t] = acc*(1.f/512.f);
}

// ---------------- legacy exp (fallback path) ----------------
__global__ void k_exp_v13(float* __restrict__ u, float* __restrict__ S){
    int b = blockIdx.x >> 8;
    size_t base = (size_t)b*262144 + (size_t)(blockIdx.x & 255)*1024;
    int t = threadIdx.x;
    float acc = 0.f;
    for (int i=t;i<1024;i+=256){ float v = expf(u[base+i]*2.0f); u[base+i]=v; acc+=v; }
    __shared__ float red[256];
    red[t]=acc; __syncthreads();
    for (int s=128;s>0;s>>=1){ if(t<s) red[t]+=red[t+s]; __syncthreads(); }
    if (t==0) atomicAdd(&S[b], red[0]);
}

// ---------------- classifier ----------------
__global__ void cls_v10(const float* __restrict__ feat, const float* __restrict__ cls_w,
                        const float* __restrict__ cls_b, float* __restrict__ out){
    int t = threadIdx.x;
    if (t < 20){
        int b = t/10, c = t%10;
        float acc = cls_b[c];
        for (int o=0; o<128; ++o)
            acc += feat[b*128+o]*cls_w[c*128+o];
        out[t] = acc;
    }
}

// ---------------- launch ----------------
extern "C" void kernel_launch(void* const* d_in, const int* in_sizes, int n_in,
                              void* d_out, int out_size, void* d_ws, size_t ws_size,
                              hipStream_t stream){
    (void)in_sizes; (void)n_in; (void)out_size;
    const float* x     = (const float*)d_in[0];
    const float* Wg    = (const float*)d_in[1];
    const float* attn  = (const float*)d_in[2];
    const float* W1    = (const float*)d_in[3];
    const float* b1    = (const float*)d_in[4];
    const float* w2    = (const float*)d_in[5];
    const float* b2    = (const float*)d_in[6];
    const float* gc1_w = (const float*)d_in[7];
    const float* gc1_b = (const float*)d_in[8];
    const float* bn1_g = (const float*)d_in[9];
    const float* bn1_b = (const float*)d_in[10];
    const float* gc2_w = (const float*)d_in[11];
    const float* gc2_b = (const float*)d_in[12];
    const float* bn2_g = (const float*)d_in[13];
    const float* bn2_b = (const float*)d_in[14];
    const float* cls_w = (const float*)d_in[15];
    const float* cls_b = (const float*)d_in[16];
    float* out = (float*)d_out;

    float *HP, *NF, *U, *PI, *PJT, *H1, *H2, *H3, *H4;
    float *STAT, *BN1S, *BN1H, *BN2S, *BN2H, *FEAT;
    float *SIbuf = nullptr, *SJbuf = nullptr, *PJ = nullptr, *ALP = nullptr;
    float *PSb = nullptr, *PS2b = nullptr, *FEATP = nullptr;
    int wsPath = (ws_size >= (size_t)22*1024*1024);

    if (wsPath){
        float* W = (float*)d_ws;
        HP  = W + 0;        NF  = W + 1048576;  H1 = W + 2097152;
        PI  = W + 3145728;  PJT = W + 3407872;  U  = W + 3670016;
        H2  = W + 4194304;  H3  = W + 4718592;  H4 = W + 5242880;
        BN1S= W + 5374208;  BN1H= W + 5374720;
        BN2S= W + 5375232;  BN2H= W + 5375360;  FEAT = W + 5375488;
        STAT= W + 5400000;
        SIbuf = W + 5500000; SJbuf = W + 5504096;
        PJ  = H2;            // H2 region free until gc1 GEMM; PJ dead by then
        ALP = PI;            // 2,097,152 floats spanning PI..H3 — dead before pipj writes PI
        PSb = W + 5420000; PS2b = W + 5430000; FEATP = W + 5440000;
    } else {
        HP  = (float*)x;
        NF  = (float*)Wg;
        PI  = (float*)x;
        PJT = (float*)x + 262144;
        U   = (float*)W1;
        H1  = (float*)x;
        H2  = (float*)Wg;
        H3  = (float*)gc1_w;
        H4  = (float*)x;
        STAT= (float*)x;
        float* A = (float*)attn;
        BN1S = A+8;    BN1H = A+520;
        BN2S = A+1032; BN2H = A+1160;  FEAT = A+1288;
    }
    float*    S    = STAT+2;
    float*    CS   = STAT+4;
    unsigned* KC   = (unsigned*)(STAT+6);
    unsigned* PFX  = (unsigned*)(STAT+8);
    unsigned* RANK = (unsigned*)(STAT+10);
    float*    THR  = STAT+12;
    float*    DINV = STAT+14;
    unsigned* H0   = (unsigned*)(STAT+16);
    unsigned* Hh1  = (unsigned*)(STAT+16+4096);
    unsigned* Hh2  = (unsigned*)(STAT+16+8192);

    if (wsPath){
        // nt#1: K-split=2, partial kz=1 -> H1 region (dead), fold into HP
        gemm64_nt<<<dim3(16,16,2),256,0,stream>>>(x, Wg, HP, 512, 1024, 1024, 1024,
                                                  nullptr, nullptr, nullptr, nullptr,
                                                  2, (long)(H1-HP));
        foldk<<<1024,256,0,stream>>>(HP, HP, (long)(H1-HP), 2, 262144);
        sij_v14 <<<64,256,0,stream>>>(HP, attn, SIbuf, SJbuf);
        asm_v17 <<<256,512,0,stream>>>(SIbuf, SJbuf, ALP);
        // PV as batched GEMM: nf[bh] = ALP[bh] @ hp[bh]  (bhmode addressing)
        gemm64_nn<<<dim3(4,8,8),256,0,stream>>>(ALP, HP, NF, 512, 512, 1024, 1024,
                                                262144, 524288, 524288, nullptr, nullptr,
                                                1, 1, 0);
        // pipj: K-split=2. PI partial1 -> PJT region; PJ(=H2) partial1 -> H2+262144.
        gemm64_nt<<<dim3(4,16,4),256,0,stream>>>(NF, W1, PI, 512, 1024, 2048, 256,
                                                 b1, W1+1024, PJ, nullptr,
                                                 2, 262144);
        foldk<<<256,256,0,stream>>>(PI, PI, 262144, 2, 65536);
        foldk<<<256,256,0,stream>>>(PJ, PJ, 262144, 2, 65536);
        transp_v15<<<dim3(4,8,2),256,0,stream>>>(PJ, PJT);
    } else {
        gemm_x_v12<<<256,256,0,stream>>>(x, Wg, HP);
        attn_v12  <<<512,256,0,stream>>>(HP, attn, NF);
        pipj_v13  <<<dim3(4,1,64),256,0,stream>>>(NF, W1, b1, PI, PJT);
    }
    edge_v12  <<<256,256,0,stream>>>(PI, PJT, w2, b2, U);
    hipMemsetAsync(STAT, 0, 10256*sizeof(float), stream);
    k_exp_v14 <<<512,256,0,stream>>>(U, S, H0);
    k_scan_v11<<<1,512,0,stream>>>(H0, 2048, PFX, RANK, 11, 1, nullptr);
    k_hist_v12<<<256,256,0,stream>>>(U, Hh1, PFX, 21, 10, 0x7FFu, 2048);
    k_scan_v11<<<1,512,0,stream>>>(Hh1, 2048, PFX, RANK, 11, 0, nullptr);
    k_hist_v12<<<256,256,0,stream>>>(U, Hh2, PFX, 10, 0, 0x3FFu, 1024);
    k_scan_v11<<<1,512,0,stream>>>(Hh2, 1024, PFX, RANK, 10, 0, THR);
    k_csum_v12<<<256,256,0,stream>>>(U, THR, CS, KC);
    k_fin_v11 <<<1,64,0,stream>>>(S, CS, KC, THR, DINV);
    adj_v10   <<<2048,256,0,stream>>>(U, THR, DINV);           // U now holds adj

    if (wsPath){
        // nn#1: K-split=2, partials kz=1 -> HP region (dead), fold into H1
        gemm64_nn<<<dim3(16,8,4),256,0,stream>>>(U, NF, H1, 256, 512, 1024, 1024,
                                                 262144, 524288, 524288, nullptr, nullptr,
                                                 0, 2, (long)(HP-H1));
        foldk<<<1024,256,0,stream>>>(H1, H1, (long)(HP-H1), 2, 262144);
        // gc1: K-split=2, partial kz=1 -> NF region (dead), fold into H2
        gemm64_nt<<<dim3(8,16,2),256,0,stream>>>(H1, gc1_w, H2, 512, 1024, 1024, 512,
                                                 gc1_b, nullptr, nullptr, nullptr,
                                                 2, (long)(NF-H2));
        foldk<<<512,256,0,stream>>>(H2, H2, (long)(NF-H2), 2, 131072);
        bnp1<<<dim3(8,16),256,0,stream>>>(H2, PSb, PS2b, 512);
        bnp2<<<8,64,0,stream>>>(PSb, PS2b, bn1_g, bn1_b, BN1S, BN1H, 512);
        // nn#2: K-split=2, partial kz=1 -> HP region, fold into H3
        gemm64_nn<<<dim3(8,8,4),256,0,stream>>>(U, H2, H3, 256, 512, 512, 512,
                                                262144, 262144, 262144, BN1S, BN1H,
                                                0, 2, (long)(HP-H3));
        foldk<<<512,256,0,stream>>>(H3, H3, (long)(HP-H3), 2, 131072);
        // gc2: K-split=4 partials into HP region, fold into H4
        gemm64_nt<<<dim3(2,16,4),256,0,stream>>>(H3, gc2_w, HP, 128, 512, 512, 128,
                                                 gc2_b, nullptr, nullptr, nullptr,
                                                 4, 131072);
        foldk<<<128,256,0,stream>>>(H4, HP, 131072, 4, 32768);
        bnp1<<<dim3(2,16),256,0,stream>>>(H4, PSb, PS2b, 128);
        bnp2<<<2,64,0,stream>>>(PSb, PS2b, bn2_g, bn2_b, BN2S, BN2H, 128);
        feat_p<<<dim3(2,8),128,0,stream>>>(H4, BN2S, BN2H, FEATP);
        feat_f<<<2,128,0,stream>>>(FEATP, FEAT);
    } else {
        gemm_nn32 <<<dim3(16,16,2),256,0,stream>>>(U, NF, H1, 512, 512, 1024, 1024,
                                                   262144, 524288, 524288, nullptr, nullptr);
        gemm_nt32 <<<dim3(8,32),256,0,stream>>>(H1, gc1_w, H2, 1024, 1024, 1024, 512, gc1_b);
        bnstats_v10<<<8,256,0,stream>>>(H2, bn1_g, bn1_b, BN1S, BN1H, 512);
        gemm_nn32 <<<dim3(8,16,2),256,0,stream>>>(U, H2, H3, 512, 512, 512, 512,
                                                  262144, 262144, 262144, BN1S, BN1H);
        gemm_nt32 <<<dim3(2,32),256,0,stream>>>(H3, gc2_w, H4, 512, 512, 512, 128, gc2_b);
        bnstats_v10<<<2,256,0,stream>>>(H4, bn2_g, bn2_b, BN2S, BN2H, 128);
        feat_v10  <<<2,128,0,stream>>>(H4, BN2S, BN2H, FEAT);
    }
    cls_v10   <<<1,64,0,stream>>>(FEAT, cls_w, cls_b, out);
}